// Round 1
// baseline (1451.755 us; speedup 1.0000x reference)
//
#include <hip/hip_runtime.h>
#include <math.h>

#define N_NODES 100000
#define N_EDGES 1600000

// ---- workspace layout (bytes), all offsets 16B-aligned ----
#define OFF_DEG      0u           // int[N]
#define OFF_CURSOR   400000u      // int[N]           (deg+cursor zeroed with one memset)
#define OFF_ROWPTR   800000u      // int[N+1] (padded)
#define OFF_INVDEG   1200016u     // float[N]
#define OFF_COL      1600016u     // int[E]
#define OFF_WPT      8000016u     // float[128*128]
#define OFF_WLT      8065552u     // float[3*128*128]
#define OFF_WRT      8262160u     // float[3*128*128]
#define OFF_WLOT     8458768u     // float[128*64]
#define OFF_WROT     8491536u     // float[128*64]
#define OFF_INP      8524304u     // float[N*128]
#define OFF_BUFA     59724304u    // float[N*128]
#define OFF_BUFB     110924304u   // float[N*128]
#define WS_NEEDED    162124304u

// ---------------- weight transpose: W[O][K] -> WT[K][O] ----------------
__global__ __launch_bounds__(256) void transpose_weights_k(
    const float* __restrict__ Wp, const float* __restrict__ Wl,
    const float* __restrict__ Wr, const float* __restrict__ Wlo,
    const float* __restrict__ Wro,
    float* __restrict__ WpT, float* __restrict__ WlT, float* __restrict__ WrT,
    float* __restrict__ WloT, float* __restrict__ WroT) {
  int i = blockIdx.x * 256 + threadIdx.x;
  if (i < 16384) {
    int o = i >> 7, k = i & 127;
    WpT[k * 128 + o] = Wp[i];
  } else if (i < 65536) {
    int j = i - 16384; int m = j >> 14; int w = j & 16383;
    int o = w >> 7, k = w & 127;
    WlT[(m << 14) + k * 128 + o] = Wl[j];
  } else if (i < 114688) {
    int j = i - 65536; int m = j >> 14; int w = j & 16383;
    int o = w >> 7, k = w & 127;
    WrT[(m << 14) + k * 128 + o] = Wr[j];
  } else if (i < 122880) {
    int j = i - 114688; int o = j >> 7, k = j & 127;
    WloT[k * 64 + o] = Wlo[j];
  } else if (i < 131072) {
    int j = i - 122880; int o = j >> 7, k = j & 127;
    WroT[k * 64 + o] = Wro[j];
  }
}

// ---------------- degree histogram ----------------
__global__ __launch_bounds__(256) void deg_hist_k(const int* __restrict__ dst,
                                                  int* __restrict__ deg) {
  int i = blockIdx.x * 256 + threadIdx.x;
  if (i < N_EDGES) atomicAdd(&deg[dst[i]], 1);
}

// ---------------- single-block exclusive scan + inv_deg ----------------
__global__ __launch_bounds__(1024) void scan_k(const int* __restrict__ deg,
                                               int* __restrict__ row_ptr,
                                               float* __restrict__ inv_deg) {
  __shared__ int ssum[1024];
  const int n = N_NODES;
  int tid = threadIdx.x;
  int per = (n + 1023) / 1024;
  int start = tid * per;
  int end = start + per; if (end > n) end = n;
  int s = 0;
  for (int i = start; i < end; i++) s += deg[i];
  ssum[tid] = s;
  __syncthreads();
  for (int off = 1; off < 1024; off <<= 1) {
    int add = (tid >= off) ? ssum[tid - off] : 0;
    __syncthreads();
    ssum[tid] += add;
    __syncthreads();
  }
  int run = ssum[tid] - s;   // exclusive prefix for this chunk
  for (int i = start; i < end; i++) {
    int d = deg[i];
    row_ptr[i] = run;
    inv_deg[i] = 1.0f / (float)(d > 1 ? d : 1);
    run += d;
  }
  if (tid == 0) row_ptr[n] = ssum[1023];
}

// ---------------- scatter edges into CSR ----------------
__global__ __launch_bounds__(256) void scatter_k(const int* __restrict__ src,
                                                 const int* __restrict__ dst,
                                                 const int* __restrict__ rp,
                                                 int* __restrict__ cursor,
                                                 int* __restrict__ col) {
  int i = blockIdx.x * 256 + threadIdx.x;
  if (i < N_EDGES) {
    int d = dst[i];
    int pos = atomicAdd(&cursor[d], 1);
    col[rp[d] + pos] = src[i];
  }
}

// ---------------- mean aggregation: one wave per node ----------------
__global__ __launch_bounds__(256) void aggregate_k(const float* __restrict__ h,
                                                   const int* __restrict__ rp,
                                                   const int* __restrict__ col,
                                                   const float* __restrict__ invdeg,
                                                   float* __restrict__ mean) {
  int wave = blockIdx.x * 4 + (threadIdx.x >> 6);
  int lane = threadIdx.x & 63;
  if (wave >= N_NODES) return;
  int beg = rp[wave], end = rp[wave + 1];
  const float* hp = h + (lane << 1);
  float ax = 0.f, ay = 0.f;
  int j = beg;
  for (; j + 1 < end; j += 2) {
    int s0 = col[j];
    int s1 = col[j + 1];
    float2 v0 = *(const float2*)(hp + ((long)s0 << 7));
    float2 v1 = *(const float2*)(hp + ((long)s1 << 7));
    ax += v0.x + v1.x;
    ay += v0.y + v1.y;
  }
  if (j < end) {
    int s0 = col[j];
    float2 v0 = *(const float2*)(hp + ((long)s0 << 7));
    ax += v0.x; ay += v0.y;
  }
  float w = invdeg[wave];
  float2 r; r.x = ax * w; r.y = ay * w;
  *(float2*)(mean + ((long)wave << 7) + (lane << 1)) = r;
}

// ---------------- inProj GEMM: h0 = X @ WpT + bp; inp = h0; h = relu(h0) ----
__global__ __launch_bounds__(256) void inproj_gemm_k(
    const float* __restrict__ X, const float* __restrict__ BT,
    const float* __restrict__ bias,
    float* __restrict__ inp, float* __restrict__ hout, int M) {
  __shared__ float As[16][64];
  __shared__ float Bs[16][128];
  int tid = threadIdx.x;
  int tx = tid & 15, ty = tid >> 4;
  int m0 = blockIdx.x * 64;
  int lr = tid >> 2;            // A-load row 0..63
  int lc = (tid & 3) << 2;      // A-load col 0,4,8,12
  int bkr = tid >> 4;           // B-load k-row 0..15
  int bc = (tid & 15) << 3;     // B-load col
  float acc[4][8] = {};
  for (int k0 = 0; k0 < 128; k0 += 16) {
    float4 av = make_float4(0.f, 0.f, 0.f, 0.f);
    int gr = m0 + lr;
    if (gr < M) av = *(const float4*)(X + (long)gr * 128 + k0 + lc);
    As[lc + 0][lr] = av.x; As[lc + 1][lr] = av.y;
    As[lc + 2][lr] = av.z; As[lc + 3][lr] = av.w;
    const float* bsrc = BT + (k0 + bkr) * 128 + bc;
    *(float4*)&Bs[bkr][bc] = *(const float4*)bsrc;
    *(float4*)&Bs[bkr][bc + 4] = *(const float4*)(bsrc + 4);
    __syncthreads();
#pragma unroll
    for (int kk = 0; kk < 16; kk++) {
      float4 a = *(const float4*)&As[kk][ty << 2];
      float4 b0 = *(const float4*)&Bs[kk][tx << 3];
      float4 b1 = *(const float4*)&Bs[kk][(tx << 3) + 4];
      float a4[4] = {a.x, a.y, a.z, a.w};
      float b8[8] = {b0.x, b0.y, b0.z, b0.w, b1.x, b1.y, b1.z, b1.w};
#pragma unroll
      for (int i = 0; i < 4; i++)
#pragma unroll
        for (int jj = 0; jj < 8; jj++) acc[i][jj] += a4[i] * b8[jj];
    }
    __syncthreads();
  }
  int c0 = tx << 3;
#pragma unroll
  for (int i = 0; i < 4; i++) {
    int r = m0 + (ty << 2) + i;
    if (r < M) {
      float z[8];
#pragma unroll
      for (int jj = 0; jj < 8; jj++) z[jj] = acc[i][jj] + bias[c0 + jj];
      float4 p0 = make_float4(z[0], z[1], z[2], z[3]);
      float4 p1 = make_float4(z[4], z[5], z[6], z[7]);
      *(float4*)(inp + (long)r * 128 + c0) = p0;
      *(float4*)(inp + (long)r * 128 + c0 + 4) = p1;
      float4 r0 = make_float4(fmaxf(z[0], 0.f), fmaxf(z[1], 0.f), fmaxf(z[2], 0.f), fmaxf(z[3], 0.f));
      float4 r1 = make_float4(fmaxf(z[4], 0.f), fmaxf(z[5], 0.f), fmaxf(z[6], 0.f), fmaxf(z[7], 0.f));
      *(float4*)(hout + (long)r * 128 + c0) = r0;
      *(float4*)(hout + (long)r * 128 + c0 + 4) = r1;
    }
  }
}

// ------- SAGE GEMM: out = relu(mean@WlT + bl + h@WrT) + 0.2*inp  (out may alias A0) -------
__global__ __launch_bounds__(256) void sage_gemm_k(
    const float* A0, const float* __restrict__ BT0,
    const float* A1, const float* __restrict__ BT1,
    const float* __restrict__ bias, const float* __restrict__ inp,
    float* outp, int M) {
  __shared__ float As[16][64];
  __shared__ float Bs[16][128];
  int tid = threadIdx.x;
  int tx = tid & 15, ty = tid >> 4;
  int m0 = blockIdx.x * 64;
  int lr = tid >> 2;
  int lc = (tid & 3) << 2;
  int bkr = tid >> 4;
  int bc = (tid & 15) << 3;
  float acc[4][8] = {};
  for (int pass = 0; pass < 2; pass++) {
    const float* A = pass ? A1 : A0;
    const float* BT = pass ? BT1 : BT0;
    for (int k0 = 0; k0 < 128; k0 += 16) {
      float4 av = make_float4(0.f, 0.f, 0.f, 0.f);
      int gr = m0 + lr;
      if (gr < M) av = *(const float4*)(A + (long)gr * 128 + k0 + lc);
      As[lc + 0][lr] = av.x; As[lc + 1][lr] = av.y;
      As[lc + 2][lr] = av.z; As[lc + 3][lr] = av.w;
      const float* bsrc = BT + (k0 + bkr) * 128 + bc;
      *(float4*)&Bs[bkr][bc] = *(const float4*)bsrc;
      *(float4*)&Bs[bkr][bc + 4] = *(const float4*)(bsrc + 4);
      __syncthreads();
#pragma unroll
      for (int kk = 0; kk < 16; kk++) {
        float4 a = *(const float4*)&As[kk][ty << 2];
        float4 b0 = *(const float4*)&Bs[kk][tx << 3];
        float4 b1 = *(const float4*)&Bs[kk][(tx << 3) + 4];
        float a4[4] = {a.x, a.y, a.z, a.w};
        float b8[8] = {b0.x, b0.y, b0.z, b0.w, b1.x, b1.y, b1.z, b1.w};
#pragma unroll
        for (int i = 0; i < 4; i++)
#pragma unroll
          for (int jj = 0; jj < 8; jj++) acc[i][jj] += a4[i] * b8[jj];
      }
      __syncthreads();
    }
  }
  int c0 = tx << 3;
#pragma unroll
  for (int i = 0; i < 4; i++) {
    int r = m0 + (ty << 2) + i;
    if (r < M) {
      float4 i0 = *(const float4*)(inp + (long)r * 128 + c0);
      float4 i1 = *(const float4*)(inp + (long)r * 128 + c0 + 4);
      float z[8];
#pragma unroll
      for (int jj = 0; jj < 8; jj++) z[jj] = fmaxf(acc[i][jj] + bias[c0 + jj], 0.f);
      float4 o0 = make_float4(z[0] + 0.2f * i0.x, z[1] + 0.2f * i0.y,
                              z[2] + 0.2f * i0.z, z[3] + 0.2f * i0.w);
      float4 o1 = make_float4(z[4] + 0.2f * i1.x, z[5] + 0.2f * i1.y,
                              z[6] + 0.2f * i1.z, z[7] + 0.2f * i1.w);
      *(float4*)(outp + (long)r * 128 + c0) = o0;
      *(float4*)(outp + (long)r * 128 + c0 + 4) = o1;
    }
  }
}

// ------- output GEMM (N=64) + fused log_softmax -------
__global__ __launch_bounds__(256) void out_gemm_k(
    const float* __restrict__ A0, const float* __restrict__ BT0,
    const float* __restrict__ A1, const float* __restrict__ BT1,
    const float* __restrict__ bias, float* __restrict__ outp, int M) {
  __shared__ float As[16][64];
  __shared__ float Bs[16][64];
  __shared__ float zt[64][65];
  __shared__ float rowoff[64];
  int tid = threadIdx.x;
  int tx = tid & 15, ty = tid >> 4;
  int m0 = blockIdx.x * 64;
  int lr = tid >> 2;
  int lc = (tid & 3) << 2;
  int bkr = tid >> 4;
  int bc = (tid & 15) << 2;
  float acc[4][4] = {};
  for (int pass = 0; pass < 2; pass++) {
    const float* A = pass ? A1 : A0;
    const float* BT = pass ? BT1 : BT0;
    for (int k0 = 0; k0 < 128; k0 += 16) {
      float4 av = make_float4(0.f, 0.f, 0.f, 0.f);
      int gr = m0 + lr;
      if (gr < M) av = *(const float4*)(A + (long)gr * 128 + k0 + lc);
      As[lc + 0][lr] = av.x; As[lc + 1][lr] = av.y;
      As[lc + 2][lr] = av.z; As[lc + 3][lr] = av.w;
      *(float4*)&Bs[bkr][bc] = *(const float4*)(BT + (k0 + bkr) * 64 + bc);
      __syncthreads();
#pragma unroll
      for (int kk = 0; kk < 16; kk++) {
        float4 a = *(const float4*)&As[kk][ty << 2];
        float4 b = *(const float4*)&Bs[kk][tx << 2];
        float a4[4] = {a.x, a.y, a.z, a.w};
        float b4[4] = {b.x, b.y, b.z, b.w};
#pragma unroll
        for (int i = 0; i < 4; i++)
#pragma unroll
          for (int jj = 0; jj < 4; jj++) acc[i][jj] += a4[i] * b4[jj];
      }
      __syncthreads();
    }
  }
  int c0 = tx << 2;
#pragma unroll
  for (int i = 0; i < 4; i++) {
    int rr = (ty << 2) + i;
#pragma unroll
    for (int jj = 0; jj < 4; jj++) zt[rr][c0 + jj] = acc[i][jj] + bias[c0 + jj];
  }
  __syncthreads();
  if (tid < 64) {
    float m = -1e30f;
#pragma unroll
    for (int c = 0; c < 64; c++) m = fmaxf(m, zt[tid][c]);
    float s = 0.f;
#pragma unroll
    for (int c = 0; c < 64; c++) s += __expf(zt[tid][c] - m);
    rowoff[tid] = m + __logf(s);
  }
  __syncthreads();
#pragma unroll
  for (int i = 0; i < 4; i++) {
    int rr = (ty << 2) + i;
    int r = m0 + rr;
    if (r < M) {
      float ro = rowoff[rr];
      float4 o = make_float4(zt[rr][c0 + 0] - ro, zt[rr][c0 + 1] - ro,
                             zt[rr][c0 + 2] - ro, zt[rr][c0 + 3] - ro);
      *(float4*)(outp + (long)r * 64 + c0) = o;
    }
  }
}

extern "C" void kernel_launch(void* const* d_in, const int* in_sizes, int n_in,
                              void* d_out, int out_size, void* d_ws, size_t ws_size,
                              hipStream_t stream) {
  if (ws_size < (size_t)WS_NEEDED) return;  // workspace too small; fail cleanly
  const float* x   = (const float*)d_in[0];
  const int*   ei  = (const int*)d_in[1];
  const float* Wp  = (const float*)d_in[2];
  const float* bp  = (const float*)d_in[3];
  const float* Wl  = (const float*)d_in[4];
  const float* bl  = (const float*)d_in[5];
  const float* Wr  = (const float*)d_in[6];
  const float* Wlo = (const float*)d_in[7];
  const float* blo = (const float*)d_in[8];
  const float* Wro = (const float*)d_in[9];
  float* out = (float*)d_out;
  char* ws = (char*)d_ws;
  int*   deg    = (int*)(ws + OFF_DEG);
  int*   cursor = (int*)(ws + OFF_CURSOR);
  int*   rp     = (int*)(ws + OFF_ROWPTR);
  float* invdeg = (float*)(ws + OFF_INVDEG);
  int*   col    = (int*)(ws + OFF_COL);
  float* WpT    = (float*)(ws + OFF_WPT);
  float* WlT    = (float*)(ws + OFF_WLT);
  float* WrT    = (float*)(ws + OFF_WRT);
  float* WloT   = (float*)(ws + OFF_WLOT);
  float* WroT   = (float*)(ws + OFF_WROT);
  float* inp    = (float*)(ws + OFF_INP);
  float* bufA   = (float*)(ws + OFF_BUFA);
  float* bufB   = (float*)(ws + OFF_BUFB);
  const int* srcv = ei;
  const int* dstv = ei + N_EDGES;

  hipMemsetAsync(ws + OFF_DEG, 0, 800000, stream);   // deg + cursor
  transpose_weights_k<<<512, 256, 0, stream>>>(Wp, Wl, Wr, Wlo, Wro,
                                               WpT, WlT, WrT, WloT, WroT);
  deg_hist_k<<<(N_EDGES + 255) / 256, 256, 0, stream>>>(dstv, deg);
  scan_k<<<1, 1024, 0, stream>>>(deg, rp, invdeg);
  scatter_k<<<(N_EDGES + 255) / 256, 256, 0, stream>>>(srcv, dstv, rp, cursor, col);

  int gblk = (N_NODES + 63) / 64;
  int ablk = (N_NODES + 3) / 4;

  inproj_gemm_k<<<gblk, 256, 0, stream>>>(x, WpT, bp, inp, bufA, N_NODES);

  // layer 1: h2 = relu(mean(h1)@Wl1 + b1 + h1@Wr1) + 0.2*inp
  aggregate_k<<<ablk, 256, 0, stream>>>(bufA, rp, col, invdeg, bufB);
  sage_gemm_k<<<gblk, 256, 0, stream>>>(bufB, WlT, bufA, WrT, bl, inp, bufB, N_NODES);
  // layer 2
  aggregate_k<<<ablk, 256, 0, stream>>>(bufB, rp, col, invdeg, bufA);
  sage_gemm_k<<<gblk, 256, 0, stream>>>(bufA, WlT + 16384, bufB, WrT + 16384,
                                        bl + 128, inp, bufA, N_NODES);
  // layer 3
  aggregate_k<<<ablk, 256, 0, stream>>>(bufA, rp, col, invdeg, bufB);
  sage_gemm_k<<<gblk, 256, 0, stream>>>(bufB, WlT + 32768, bufA, WrT + 32768,
                                        bl + 256, inp, bufB, N_NODES);
  // output layer + log_softmax
  aggregate_k<<<ablk, 256, 0, stream>>>(bufB, rp, col, invdeg, bufA);
  out_gemm_k<<<gblk, 256, 0, stream>>>(bufA, WloT, bufB, WroT, blo, out, N_NODES);
}

// Round 2
// 1232.108 us; speedup vs baseline: 1.1783x; 1.1783x over previous
//
#include <hip/hip_runtime.h>
#include <math.h>

#define N_NODES 100000
#define N_EDGES 1600000
#define NB_SCAN 391   // ceil(N/256)

// ---- workspace layout (bytes), all offsets 16B-aligned ----
#define OFF_DEG      0u           // int[N]
#define OFF_CURSOR   400000u      // int[N]           (deg+cursor zeroed with one memset)
#define OFF_ROWPTR   800000u      // int[N+1] (padded)
#define OFF_INVDEG   1200016u     // float[N]
#define OFF_COL      1600016u     // int[E]  (first 4KB reused as scan temporaries pre-scatter)
#define OFF_WPT      8000016u     // float[128*128]
#define OFF_WLT      8065552u     // float[3*128*128]
#define OFF_WRT      8262160u     // float[3*128*128]
#define OFF_WLOT     8458768u     // float[128*64]
#define OFF_WROT     8491536u     // float[128*64]
#define OFF_INP      8524304u     // float[N*128]
#define OFF_BUFA     59724304u    // float[N*128]
#define OFF_BUFB     110924304u   // float[N*128]
#define WS_NEEDED    162124304u

// ---------------- weight transpose: W[O][K] -> WT[K][O] ----------------
__global__ __launch_bounds__(256) void transpose_weights_k(
    const float* __restrict__ Wp, const float* __restrict__ Wl,
    const float* __restrict__ Wr, const float* __restrict__ Wlo,
    const float* __restrict__ Wro,
    float* __restrict__ WpT, float* __restrict__ WlT, float* __restrict__ WrT,
    float* __restrict__ WloT, float* __restrict__ WroT) {
  int i = blockIdx.x * 256 + threadIdx.x;
  if (i < 16384) {
    int o = i >> 7, k = i & 127;
    WpT[k * 128 + o] = Wp[i];
  } else if (i < 65536) {
    int j = i - 16384; int m = j >> 14; int w = j & 16383;
    int o = w >> 7, k = w & 127;
    WlT[(m << 14) + k * 128 + o] = Wl[j];
  } else if (i < 114688) {
    int j = i - 65536; int m = j >> 14; int w = j & 16383;
    int o = w >> 7, k = w & 127;
    WrT[(m << 14) + k * 128 + o] = Wr[j];
  } else if (i < 122880) {
    int j = i - 114688; int o = j >> 7, k = j & 127;
    WloT[k * 64 + o] = Wlo[j];
  } else if (i < 131072) {
    int j = i - 122880; int o = j >> 7, k = j & 127;
    WroT[k * 64 + o] = Wro[j];
  }
}

// ---------------- degree histogram ----------------
__global__ __launch_bounds__(256) void deg_hist_k(const int* __restrict__ dst,
                                                  int* __restrict__ deg) {
  int i = blockIdx.x * 256 + threadIdx.x;
  if (i < N_EDGES) atomicAdd(&deg[dst[i]], 1);
}

// -------- parallel scan, phase 1: per-block exclusive scan + block sums --------
__global__ __launch_bounds__(256) void scan1_k(const int* __restrict__ deg,
                                               int* __restrict__ rp,
                                               int* __restrict__ bsum) {
  __shared__ int s[256];
  int t = threadIdx.x;
  int i = blockIdx.x * 256 + t;
  int d = (i < N_NODES) ? deg[i] : 0;
  s[t] = d;
  __syncthreads();
  for (int off = 1; off < 256; off <<= 1) {
    int v = (t >= off) ? s[t - off] : 0;
    __syncthreads();
    s[t] += v;
    __syncthreads();
  }
  if (i < N_NODES) rp[i] = s[t] - d;            // exclusive within block
  if (t == 255) bsum[blockIdx.x] = s[255];      // block total
}

// -------- phase 2: single-block scan of the 391 block sums --------
__global__ __launch_bounds__(512) void scan2_k(const int* __restrict__ bsum,
                                               int* __restrict__ boff,
                                               int* __restrict__ rp) {
  __shared__ int s[512];
  int t = threadIdx.x;
  int v = (t < NB_SCAN) ? bsum[t] : 0;
  s[t] = v;
  __syncthreads();
  for (int off = 1; off < 512; off <<= 1) {
    int u = (t >= off) ? s[t - off] : 0;
    __syncthreads();
    s[t] += u;
    __syncthreads();
  }
  if (t < NB_SCAN) boff[t] = s[t] - v;          // exclusive block offset
  if (t == 511) rp[N_NODES] = s[511];           // grand total (= E)
}

// -------- phase 3: add block offsets; inv_deg --------
__global__ __launch_bounds__(256) void scan3_k(const int* __restrict__ deg,
                                               const int* __restrict__ boff,
                                               int* __restrict__ rp,
                                               float* __restrict__ inv_deg) {
  int i = blockIdx.x * 256 + threadIdx.x;
  if (i < N_NODES) {
    rp[i] += boff[blockIdx.x];
    int d = deg[i];
    inv_deg[i] = 1.0f / (float)(d > 1 ? d : 1);
  }
}

// ---------------- scatter edges into CSR ----------------
__global__ __launch_bounds__(256) void scatter_k(const int* __restrict__ src,
                                                 const int* __restrict__ dst,
                                                 const int* __restrict__ rp,
                                                 int* __restrict__ cursor,
                                                 int* __restrict__ col) {
  int i = blockIdx.x * 256 + threadIdx.x;
  if (i < N_EDGES) {
    int d = dst[i];
    int pos = atomicAdd(&cursor[d], 1);
    col[rp[d] + pos] = src[i];
  }
}

// ---------------- mean aggregation: one half-wave (32 lanes) per node ----------------
__global__ __launch_bounds__(256) void aggregate_k(const float* __restrict__ h,
                                                   const int* __restrict__ rp,
                                                   const int* __restrict__ col,
                                                   const float* __restrict__ invdeg,
                                                   float* __restrict__ mean) {
  int node = blockIdx.x * 8 + (threadIdx.x >> 5);
  int lane = threadIdx.x & 31;
  if (node >= N_NODES) return;
  int beg = rp[node], end = rp[node + 1];
  const float* hp = h + (lane << 2);
  float ax = 0.f, ay = 0.f, az = 0.f, aw = 0.f;
  int j = beg;
  for (; j + 1 < end; j += 2) {
    int s0 = col[j];
    int s1 = col[j + 1];
    float4 v0 = *(const float4*)(hp + ((long)s0 << 7));
    float4 v1 = *(const float4*)(hp + ((long)s1 << 7));
    ax += v0.x + v1.x;
    ay += v0.y + v1.y;
    az += v0.z + v1.z;
    aw += v0.w + v1.w;
  }
  if (j < end) {
    int s0 = col[j];
    float4 v0 = *(const float4*)(hp + ((long)s0 << 7));
    ax += v0.x; ay += v0.y; az += v0.z; aw += v0.w;
  }
  float w = invdeg[node];
  float4 r; r.x = ax * w; r.y = ay * w; r.z = az * w; r.w = aw * w;
  *(float4*)(mean + ((long)node << 7) + (lane << 2)) = r;
}

// ---------------- inProj GEMM: h0 = X @ WpT + bp; inp = h0; h = relu(h0) ----
__global__ __launch_bounds__(256) void inproj_gemm_k(
    const float* __restrict__ X, const float* __restrict__ BT,
    const float* __restrict__ bias,
    float* __restrict__ inp, float* __restrict__ hout, int M) {
  __shared__ float As[16][64];
  __shared__ float Bs[16][128];
  int tid = threadIdx.x;
  int tx = tid & 15, ty = tid >> 4;
  int m0 = blockIdx.x * 64;
  int lr = tid >> 2;            // A-load row 0..63
  int lc = (tid & 3) << 2;      // A-load col 0,4,8,12
  int bkr = tid >> 4;           // B-load k-row 0..15
  int bc = (tid & 15) << 3;     // B-load col
  float acc[4][8] = {};
  for (int k0 = 0; k0 < 128; k0 += 16) {
    float4 av = make_float4(0.f, 0.f, 0.f, 0.f);
    int gr = m0 + lr;
    if (gr < M) av = *(const float4*)(X + (long)gr * 128 + k0 + lc);
    As[lc + 0][lr] = av.x; As[lc + 1][lr] = av.y;
    As[lc + 2][lr] = av.z; As[lc + 3][lr] = av.w;
    const float* bsrc = BT + (k0 + bkr) * 128 + bc;
    *(float4*)&Bs[bkr][bc] = *(const float4*)bsrc;
    *(float4*)&Bs[bkr][bc + 4] = *(const float4*)(bsrc + 4);
    __syncthreads();
#pragma unroll
    for (int kk = 0; kk < 16; kk++) {
      float4 a = *(const float4*)&As[kk][ty << 2];
      float4 b0 = *(const float4*)&Bs[kk][tx << 3];
      float4 b1 = *(const float4*)&Bs[kk][(tx << 3) + 4];
      float a4[4] = {a.x, a.y, a.z, a.w};
      float b8[8] = {b0.x, b0.y, b0.z, b0.w, b1.x, b1.y, b1.z, b1.w};
#pragma unroll
      for (int i = 0; i < 4; i++)
#pragma unroll
        for (int jj = 0; jj < 8; jj++) acc[i][jj] += a4[i] * b8[jj];
    }
    __syncthreads();
  }
  int c0 = tx << 3;
#pragma unroll
  for (int i = 0; i < 4; i++) {
    int r = m0 + (ty << 2) + i;
    if (r < M) {
      float z[8];
#pragma unroll
      for (int jj = 0; jj < 8; jj++) z[jj] = acc[i][jj] + bias[c0 + jj];
      float4 p0 = make_float4(z[0], z[1], z[2], z[3]);
      float4 p1 = make_float4(z[4], z[5], z[6], z[7]);
      *(float4*)(inp + (long)r * 128 + c0) = p0;
      *(float4*)(inp + (long)r * 128 + c0 + 4) = p1;
      float4 r0 = make_float4(fmaxf(z[0], 0.f), fmaxf(z[1], 0.f), fmaxf(z[2], 0.f), fmaxf(z[3], 0.f));
      float4 r1 = make_float4(fmaxf(z[4], 0.f), fmaxf(z[5], 0.f), fmaxf(z[6], 0.f), fmaxf(z[7], 0.f));
      *(float4*)(hout + (long)r * 128 + c0) = r0;
      *(float4*)(hout + (long)r * 128 + c0 + 4) = r1;
    }
  }
}

// ------- SAGE GEMM: out = relu(mean@WlT + bl + h@WrT) + 0.2*inp  (out may alias A0) -------
__global__ __launch_bounds__(256) void sage_gemm_k(
    const float* A0, const float* __restrict__ BT0,
    const float* A1, const float* __restrict__ BT1,
    const float* __restrict__ bias, const float* __restrict__ inp,
    float* outp, int M) {
  __shared__ float As[16][64];
  __shared__ float Bs[16][128];
  int tid = threadIdx.x;
  int tx = tid & 15, ty = tid >> 4;
  int m0 = blockIdx.x * 64;
  int lr = tid >> 2;
  int lc = (tid & 3) << 2;
  int bkr = tid >> 4;
  int bc = (tid & 15) << 3;
  float acc[4][8] = {};
  for (int pass = 0; pass < 2; pass++) {
    const float* A = pass ? A1 : A0;
    const float* BT = pass ? BT1 : BT0;
    for (int k0 = 0; k0 < 128; k0 += 16) {
      float4 av = make_float4(0.f, 0.f, 0.f, 0.f);
      int gr = m0 + lr;
      if (gr < M) av = *(const float4*)(A + (long)gr * 128 + k0 + lc);
      As[lc + 0][lr] = av.x; As[lc + 1][lr] = av.y;
      As[lc + 2][lr] = av.z; As[lc + 3][lr] = av.w;
      const float* bsrc = BT + (k0 + bkr) * 128 + bc;
      *(float4*)&Bs[bkr][bc] = *(const float4*)bsrc;
      *(float4*)&Bs[bkr][bc + 4] = *(const float4*)(bsrc + 4);
      __syncthreads();
#pragma unroll
      for (int kk = 0; kk < 16; kk++) {
        float4 a = *(const float4*)&As[kk][ty << 2];
        float4 b0 = *(const float4*)&Bs[kk][tx << 3];
        float4 b1 = *(const float4*)&Bs[kk][(tx << 3) + 4];
        float a4[4] = {a.x, a.y, a.z, a.w};
        float b8[8] = {b0.x, b0.y, b0.z, b0.w, b1.x, b1.y, b1.z, b1.w};
#pragma unroll
        for (int i = 0; i < 4; i++)
#pragma unroll
          for (int jj = 0; jj < 8; jj++) acc[i][jj] += a4[i] * b8[jj];
      }
      __syncthreads();
    }
  }
  int c0 = tx << 3;
#pragma unroll
  for (int i = 0; i < 4; i++) {
    int r = m0 + (ty << 2) + i;
    if (r < M) {
      float4 i0 = *(const float4*)(inp + (long)r * 128 + c0);
      float4 i1 = *(const float4*)(inp + (long)r * 128 + c0 + 4);
      float z[8];
#pragma unroll
      for (int jj = 0; jj < 8; jj++) z[jj] = fmaxf(acc[i][jj] + bias[c0 + jj], 0.f);
      float4 o0 = make_float4(z[0] + 0.2f * i0.x, z[1] + 0.2f * i0.y,
                              z[2] + 0.2f * i0.z, z[3] + 0.2f * i0.w);
      float4 o1 = make_float4(z[4] + 0.2f * i1.x, z[5] + 0.2f * i1.y,
                              z[6] + 0.2f * i1.z, z[7] + 0.2f * i1.w);
      *(float4*)(outp + (long)r * 128 + c0) = o0;
      *(float4*)(outp + (long)r * 128 + c0 + 4) = o1;
    }
  }
}

// ------- output GEMM (N=64) + fused log_softmax -------
__global__ __launch_bounds__(256) void out_gemm_k(
    const float* __restrict__ A0, const float* __restrict__ BT0,
    const float* __restrict__ A1, const float* __restrict__ BT1,
    const float* __restrict__ bias, float* __restrict__ outp, int M) {
  __shared__ float As[16][64];
  __shared__ float Bs[16][64];
  __shared__ float zt[64][65];
  __shared__ float rowoff[64];
  int tid = threadIdx.x;
  int tx = tid & 15, ty = tid >> 4;
  int m0 = blockIdx.x * 64;
  int lr = tid >> 2;
  int lc = (tid & 3) << 2;
  int bkr = tid >> 4;
  int bc = (tid & 15) << 2;
  float acc[4][4] = {};
  for (int pass = 0; pass < 2; pass++) {
    const float* A = pass ? A1 : A0;
    const float* BT = pass ? BT1 : BT0;
    for (int k0 = 0; k0 < 128; k0 += 16) {
      float4 av = make_float4(0.f, 0.f, 0.f, 0.f);
      int gr = m0 + lr;
      if (gr < M) av = *(const float4*)(A + (long)gr * 128 + k0 + lc);
      As[lc + 0][lr] = av.x; As[lc + 1][lr] = av.y;
      As[lc + 2][lr] = av.z; As[lc + 3][lr] = av.w;
      *(float4*)&Bs[bkr][bc] = *(const float4*)(BT + (k0 + bkr) * 64 + bc);
      __syncthreads();
#pragma unroll
      for (int kk = 0; kk < 16; kk++) {
        float4 a = *(const float4*)&As[kk][ty << 2];
        float4 b = *(const float4*)&Bs[kk][tx << 2];
        float a4[4] = {a.x, a.y, a.z, a.w};
        float b4[4] = {b.x, b.y, b.z, b.w};
#pragma unroll
        for (int i = 0; i < 4; i++)
#pragma unroll
          for (int jj = 0; jj < 4; jj++) acc[i][jj] += a4[i] * b4[jj];
      }
      __syncthreads();
    }
  }
  int c0 = tx << 2;
#pragma unroll
  for (int i = 0; i < 4; i++) {
    int rr = (ty << 2) + i;
#pragma unroll
    for (int jj = 0; jj < 4; jj++) zt[rr][c0 + jj] = acc[i][jj] + bias[c0 + jj];
  }
  __syncthreads();
  if (tid < 64) {
    float m = -1e30f;
#pragma unroll
    for (int c = 0; c < 64; c++) m = fmaxf(m, zt[tid][c]);
    float s = 0.f;
#pragma unroll
    for (int c = 0; c < 64; c++) s += __expf(zt[tid][c] - m);
    rowoff[tid] = m + __logf(s);
  }
  __syncthreads();
#pragma unroll
  for (int i = 0; i < 4; i++) {
    int rr = (ty << 2) + i;
    int r = m0 + rr;
    if (r < M) {
      float ro = rowoff[rr];
      float4 o = make_float4(zt[rr][c0 + 0] - ro, zt[rr][c0 + 1] - ro,
                             zt[rr][c0 + 2] - ro, zt[rr][c0 + 3] - ro);
      *(float4*)(outp + (long)r * 64 + c0) = o;
    }
  }
}

extern "C" void kernel_launch(void* const* d_in, const int* in_sizes, int n_in,
                              void* d_out, int out_size, void* d_ws, size_t ws_size,
                              hipStream_t stream) {
  if (ws_size < (size_t)WS_NEEDED) return;  // workspace too small; fail cleanly
  const float* x   = (const float*)d_in[0];
  const int*   ei  = (const int*)d_in[1];
  const float* Wp  = (const float*)d_in[2];
  const float* bp  = (const float*)d_in[3];
  const float* Wl  = (const float*)d_in[4];
  const float* bl  = (const float*)d_in[5];
  const float* Wr  = (const float*)d_in[6];
  const float* Wlo = (const float*)d_in[7];
  const float* blo = (const float*)d_in[8];
  const float* Wro = (const float*)d_in[9];
  float* out = (float*)d_out;
  char* ws = (char*)d_ws;
  int*   deg    = (int*)(ws + OFF_DEG);
  int*   cursor = (int*)(ws + OFF_CURSOR);
  int*   rp     = (int*)(ws + OFF_ROWPTR);
  float* invdeg = (float*)(ws + OFF_INVDEG);
  int*   col    = (int*)(ws + OFF_COL);
  // scan temporaries live in the (not-yet-written) col region, pre-scatter
  int*   bsum   = (int*)(ws + OFF_COL);
  int*   boff   = (int*)(ws + OFF_COL + 2048);
  float* WpT    = (float*)(ws + OFF_WPT);
  float* WlT    = (float*)(ws + OFF_WLT);
  float* WrT    = (float*)(ws + OFF_WRT);
  float* WloT   = (float*)(ws + OFF_WLOT);
  float* WroT   = (float*)(ws + OFF_WROT);
  float* inp    = (float*)(ws + OFF_INP);
  float* bufA   = (float*)(ws + OFF_BUFA);
  float* bufB   = (float*)(ws + OFF_BUFB);
  const int* srcv = ei;
  const int* dstv = ei + N_EDGES;

  hipMemsetAsync(ws + OFF_DEG, 0, 800000, stream);   // deg + cursor
  transpose_weights_k<<<512, 256, 0, stream>>>(Wp, Wl, Wr, Wlo, Wro,
                                               WpT, WlT, WrT, WloT, WroT);
  deg_hist_k<<<(N_EDGES + 255) / 256, 256, 0, stream>>>(dstv, deg);
  scan1_k<<<NB_SCAN, 256, 0, stream>>>(deg, rp, bsum);
  scan2_k<<<1, 512, 0, stream>>>(bsum, boff, rp);
  scan3_k<<<NB_SCAN, 256, 0, stream>>>(deg, boff, rp, invdeg);
  scatter_k<<<(N_EDGES + 255) / 256, 256, 0, stream>>>(srcv, dstv, rp, cursor, col);

  int gblk = (N_NODES + 63) / 64;
  int ablk = (N_NODES + 7) / 8;

  inproj_gemm_k<<<gblk, 256, 0, stream>>>(x, WpT, bp, inp, bufA, N_NODES);

  // layer 1: h2 = relu(mean(h1)@Wl1 + b1 + h1@Wr1) + 0.2*inp
  aggregate_k<<<ablk, 256, 0, stream>>>(bufA, rp, col, invdeg, bufB);
  sage_gemm_k<<<gblk, 256, 0, stream>>>(bufB, WlT, bufA, WrT, bl, inp, bufB, N_NODES);
  // layer 2
  aggregate_k<<<ablk, 256, 0, stream>>>(bufB, rp, col, invdeg, bufA);
  sage_gemm_k<<<gblk, 256, 0, stream>>>(bufA, WlT + 16384, bufB, WrT + 16384,
                                        bl + 128, inp, bufA, N_NODES);
  // layer 3
  aggregate_k<<<ablk, 256, 0, stream>>>(bufA, rp, col, invdeg, bufB);
  sage_gemm_k<<<gblk, 256, 0, stream>>>(bufB, WlT + 32768, bufA, WrT + 32768,
                                        bl + 256, inp, bufB, N_NODES);
  // output layer + log_softmax
  aggregate_k<<<ablk, 256, 0, stream>>>(bufB, rp, col, invdeg, bufA);
  out_gemm_k<<<gblk, 256, 0, stream>>>(bufA, WloT, bufB, WroT, blo, out, N_NODES);
}

// Round 3
// 870.327 us; speedup vs baseline: 1.6681x; 1.4157x over previous
//
#include <hip/hip_runtime.h>
#include <math.h>

#define N_NODES 100000
#define N_EDGES 1600000
#define NB_SCAN 391   // ceil(N/256)

typedef unsigned short u16;
typedef __bf16 bf16x8 __attribute__((ext_vector_type(8)));
typedef float f32x4 __attribute__((ext_vector_type(4)));

// ---- workspace layout (bytes), all offsets 16B-aligned ----
#define OFF_DEG      0u           // int[N]
#define OFF_CURSOR   400000u      // int[N]   (deg+cursor zeroed with one memset)
#define OFF_ROWPTR   800000u      // int[N+1]
#define OFF_INVDEG   1200016u     // float[N]
#define OFF_COL      1600016u     // int[E] (first KBs reused as scan temps pre-scatter)
#define OFF_PACK     8000016u     // u16[131072] packed bf16 weight fragments
#define OFF_INP      8262160u     // u16[N*128] residual (pre-relu inProj out), bf16
#define OFF_BUFA     33862160u    // u16[N*128] h, bf16
#define OFF_BUFB     59462160u    // u16[N*128] mean / xb scratch, bf16
#define WS_NEEDED    85062160u

// packed-weight element offsets (u16 units)
#define PK_WP   0
#define PK_WL   16384
#define PK_WR   65536
#define PK_WLO  114688
#define PK_WRO  122880

__device__ __forceinline__ float bfl(unsigned u) {  // low bf16 of a u32 pair
  union { unsigned i; float f; } v; v.i = u << 16; return v.f;
}
__device__ __forceinline__ float bfh(unsigned u) {  // high bf16
  union { unsigned i; float f; } v; v.i = u & 0xFFFF0000u; return v.f;
}
__device__ __forceinline__ float b2f(u16 u) {
  union { unsigned i; float f; } v; v.i = ((unsigned)u) << 16; return v.f;
}
__device__ __forceinline__ u16 f2b(float f) {       // RTNE
  union { float f; unsigned i; } v; v.f = f;
  unsigned r = (v.i + 0x7FFFu + ((v.i >> 16) & 1u)) >> 16;
  return (u16)r;
}

// ---------------- pack fp32 weights -> bf16 MFMA B-fragments ----------------
// For W[O][K] (B[k][n]=W[n][k]): frag (kt,nt,lane) holds B[kt*32+(lane>>4)*8+j][nt*16+(lane&15)]
// = W[n][k0..k0+8) -> 8 contiguous fp32 -> 8 bf16. Layout P[kt][nt][lane][8].
__global__ __launch_bounds__(256) void pack_weights_k(
    const float* __restrict__ Wp, const float* __restrict__ Wl,
    const float* __restrict__ Wr, const float* __restrict__ Wlo,
    const float* __restrict__ Wro, u16* __restrict__ P) {
  int t = blockIdx.x * 256 + threadIdx.x;
  if (t >= 16384) return;
  const float* W; u16* dst; int j; int NT;
  if (t < 2048)        { W = Wp;                    dst = P + PK_WP;                j = t;                 NT = 8; }
  else if (t < 8192)   { int m = (t - 2048) >> 11;  j = (t - 2048) & 2047;
                         W = Wl + (m << 14);        dst = P + PK_WL + (m << 14);    NT = 8; }
  else if (t < 14336)  { int m = (t - 8192) >> 11;  j = (t - 8192) & 2047;
                         W = Wr + (m << 14);        dst = P + PK_WR + (m << 14);    NT = 8; }
  else if (t < 15360)  { j = t - 14336;             W = Wlo;  dst = P + PK_WLO;     NT = 4; }
  else                 { j = t - 15360;             W = Wro;  dst = P + PK_WRO;     NT = 4; }
  int lane = j & 63;
  int nt, kt;
  if (NT == 8) { nt = (j >> 6) & 7; kt = j >> 9; }
  else         { nt = (j >> 6) & 3; kt = j >> 8; }
  int n  = nt * 16 + (lane & 15);
  int k0 = kt * 32 + ((lane >> 4) << 3);
  const float* s = W + n * 128 + k0;
  ushort4 lo = make_ushort4(f2b(s[0]), f2b(s[1]), f2b(s[2]), f2b(s[3]));
  ushort4 hi = make_ushort4(f2b(s[4]), f2b(s[5]), f2b(s[6]), f2b(s[7]));
  *(ushort4*)(dst + j * 8)     = lo;
  *(ushort4*)(dst + j * 8 + 4) = hi;
}

// ---------------- fp32 -> bf16 bulk convert (x -> xb) ----------------
__global__ __launch_bounds__(256) void f2bf_k(const float* __restrict__ x,
                                              u16* __restrict__ xb, int n4) {
  int i = blockIdx.x * 256 + threadIdx.x;
  if (i < n4) {
    float4 v = ((const float4*)x)[i];
    ushort4 o = make_ushort4(f2b(v.x), f2b(v.y), f2b(v.z), f2b(v.w));
    ((ushort4*)xb)[i] = o;
  }
}

// ---------------- degree histogram ----------------
__global__ __launch_bounds__(256) void deg_hist_k(const int* __restrict__ dst,
                                                  int* __restrict__ deg) {
  int i = blockIdx.x * 256 + threadIdx.x;
  if (i < N_EDGES) atomicAdd(&deg[dst[i]], 1);
}

// -------- parallel scan, phase 1 --------
__global__ __launch_bounds__(256) void scan1_k(const int* __restrict__ deg,
                                               int* __restrict__ rp,
                                               int* __restrict__ bsum) {
  __shared__ int s[256];
  int t = threadIdx.x;
  int i = blockIdx.x * 256 + t;
  int d = (i < N_NODES) ? deg[i] : 0;
  s[t] = d;
  __syncthreads();
  for (int off = 1; off < 256; off <<= 1) {
    int v = (t >= off) ? s[t - off] : 0;
    __syncthreads();
    s[t] += v;
    __syncthreads();
  }
  if (i < N_NODES) rp[i] = s[t] - d;
  if (t == 255) bsum[blockIdx.x] = s[255];
}

// -------- phase 2 --------
__global__ __launch_bounds__(512) void scan2_k(const int* __restrict__ bsum,
                                               int* __restrict__ boff,
                                               int* __restrict__ rp) {
  __shared__ int s[512];
  int t = threadIdx.x;
  int v = (t < NB_SCAN) ? bsum[t] : 0;
  s[t] = v;
  __syncthreads();
  for (int off = 1; off < 512; off <<= 1) {
    int u = (t >= off) ? s[t - off] : 0;
    __syncthreads();
    s[t] += u;
    __syncthreads();
  }
  if (t < NB_SCAN) boff[t] = s[t] - v;
  if (t == 511) rp[N_NODES] = s[511];
}

// -------- phase 3 --------
__global__ __launch_bounds__(256) void scan3_k(const int* __restrict__ deg,
                                               const int* __restrict__ boff,
                                               int* __restrict__ rp,
                                               float* __restrict__ inv_deg) {
  int i = blockIdx.x * 256 + threadIdx.x;
  if (i < N_NODES) {
    rp[i] += boff[blockIdx.x];
    int d = deg[i];
    inv_deg[i] = 1.0f / (float)(d > 1 ? d : 1);
  }
}

// ---------------- scatter edges into CSR ----------------
__global__ __launch_bounds__(256) void scatter_k(const int* __restrict__ src,
                                                 const int* __restrict__ dst,
                                                 const int* __restrict__ rp,
                                                 int* __restrict__ cursor,
                                                 int* __restrict__ col) {
  int i = blockIdx.x * 256 + threadIdx.x;
  if (i < N_EDGES) {
    int d = dst[i];
    int pos = atomicAdd(&cursor[d], 1);
    col[rp[d] + pos] = src[i];
  }
}

// ------- mean aggregation (bf16 rows): half-wave per node, 8B loads -------
__global__ __launch_bounds__(256) void aggregate_bf_k(const u16* __restrict__ h,
                                                      const int* __restrict__ rp,
                                                      const int* __restrict__ col,
                                                      const float* __restrict__ invdeg,
                                                      u16* __restrict__ mean) {
  int node = blockIdx.x * 8 + (threadIdx.x >> 5);
  int lane = threadIdx.x & 31;
  if (node >= N_NODES) return;
  int beg = rp[node], end = rp[node + 1];
  const u16* hp = h + lane * 4;
  float a0 = 0.f, a1 = 0.f, a2 = 0.f, a3 = 0.f;
  int j = beg;
  for (; j + 1 < end; j += 2) {
    int s0 = col[j];
    int s1 = col[j + 1];
    uint2 v0 = *(const uint2*)(hp + ((long)s0 << 7));
    uint2 v1 = *(const uint2*)(hp + ((long)s1 << 7));
    a0 += bfl(v0.x) + bfl(v1.x);
    a1 += bfh(v0.x) + bfh(v1.x);
    a2 += bfl(v0.y) + bfl(v1.y);
    a3 += bfh(v0.y) + bfh(v1.y);
  }
  if (j < end) {
    uint2 v0 = *(const uint2*)(hp + ((long)col[j] << 7));
    a0 += bfl(v0.x); a1 += bfh(v0.x); a2 += bfl(v0.y); a3 += bfh(v0.y);
  }
  float w = invdeg[node];
  ushort4 r = make_ushort4(f2b(a0 * w), f2b(a1 * w), f2b(a2 * w), f2b(a3 * w));
  *(ushort4*)(mean + ((long)node << 7) + lane * 4) = r;
}

// ======== MFMA GEMM family: block = 4 waves, each wave 16 rows x N cols ========
// a_frag: A[m=lane&15][k=quad*8+j] (16B contiguous load from bf16 row)
// b_frag: packed P[kt][nt][lane][8]
// C/D: D[row=quad*4+reg][col=nt*16+(lane&15)]

// ------- inProj: z = xb@WpT + bp; inp=bf16(z); hA=bf16(relu(z)) -------
__global__ __launch_bounds__(256) void inproj_mfma_k(
    const u16* __restrict__ A, const u16* __restrict__ P,
    const float* __restrict__ bias,
    u16* __restrict__ inp, u16* __restrict__ hout, int M) {
  __shared__ float zb[4 * 16 * 132];
  int tid = threadIdx.x;
  int w = tid >> 6, lane = tid & 63;
  int quad = lane >> 4, l15 = lane & 15;
  int m0 = blockIdx.x * 64;
  int rowa = m0 + w * 16 + l15; if (rowa > M - 1) rowa = M - 1;
  f32x4 acc[8] = {};
#pragma unroll
  for (int kt = 0; kt < 4; kt++) {
    bf16x8 af = *(const bf16x8*)(A + (long)rowa * 128 + kt * 32 + quad * 8);
    const u16* pb = P + ((kt * 8) * 64 + lane) * 8;
#pragma unroll
    for (int nt = 0; nt < 8; nt++) {
      bf16x8 bf = *(const bf16x8*)(pb + nt * 512);
      acc[nt] = __builtin_amdgcn_mfma_f32_16x16x32_bf16(af, bf, acc[nt], 0, 0, 0);
    }
  }
  // regs -> LDS (raw z = acc + bias)
#pragma unroll
  for (int nt = 0; nt < 8; nt++) {
    int c = nt * 16 + l15;
    float b = bias[c];
#pragma unroll
    for (int r = 0; r < 4; r++)
      zb[(w * 16 + quad * 4 + r) * 132 + c] = acc[nt][r] + b;
  }
  __syncthreads();
  int r = lane >> 2, seg = lane & 3;
  long grow = m0 + w * 16 + r;
  if (grow < M) {
    const float* zrow = &zb[(w * 16 + r) * 132 + seg * 32];
    u16* ip = inp + grow * 128 + seg * 32;
    u16* hp = hout + grow * 128 + seg * 32;
#pragma unroll
    for (int b = 0; b < 4; b++) {
      float zv[8];
      *(float4*)&zv[0] = *(const float4*)(zrow + b * 8);
      *(float4*)&zv[4] = *(const float4*)(zrow + b * 8 + 4);
      ushort4 o0 = make_ushort4(f2b(zv[0]), f2b(zv[1]), f2b(zv[2]), f2b(zv[3]));
      ushort4 o1 = make_ushort4(f2b(zv[4]), f2b(zv[5]), f2b(zv[6]), f2b(zv[7]));
      ushort4 r0 = make_ushort4(f2b(fmaxf(zv[0], 0.f)), f2b(fmaxf(zv[1], 0.f)),
                                f2b(fmaxf(zv[2], 0.f)), f2b(fmaxf(zv[3], 0.f)));
      ushort4 r1 = make_ushort4(f2b(fmaxf(zv[4], 0.f)), f2b(fmaxf(zv[5], 0.f)),
                                f2b(fmaxf(zv[6], 0.f)), f2b(fmaxf(zv[7], 0.f)));
      *(ushort4*)(ip + b * 8) = o0; *(ushort4*)(ip + b * 8 + 4) = o1;
      *(ushort4*)(hp + b * 8) = r0; *(ushort4*)(hp + b * 8 + 4) = r1;
    }
  }
}

// ------- SAGE layer: h = bf16(relu(mean@Wl + bl + h@Wr) + 0.2*inp), in-place on A1 -------
__global__ __launch_bounds__(256) void sage_mfma_k(
    const u16* __restrict__ A0, const u16* __restrict__ P0,
    const u16* __restrict__ A1, const u16* __restrict__ P1,
    const float* __restrict__ bias, const u16* __restrict__ inp,
    u16* __restrict__ outp, int M) {
  __shared__ float zb[4 * 16 * 132];
  int tid = threadIdx.x;
  int w = tid >> 6, lane = tid & 63;
  int quad = lane >> 4, l15 = lane & 15;
  int m0 = blockIdx.x * 64;
  int rowa = m0 + w * 16 + l15; if (rowa > M - 1) rowa = M - 1;
  f32x4 acc[8] = {};
#pragma unroll
  for (int pass = 0; pass < 2; pass++) {
    const u16* A = pass ? A1 : A0;
    const u16* P = pass ? P1 : P0;
#pragma unroll
    for (int kt = 0; kt < 4; kt++) {
      bf16x8 af = *(const bf16x8*)(A + (long)rowa * 128 + kt * 32 + quad * 8);
      const u16* pb = P + ((kt * 8) * 64 + lane) * 8;
#pragma unroll
      for (int nt = 0; nt < 8; nt++) {
        bf16x8 bf = *(const bf16x8*)(pb + nt * 512);
        acc[nt] = __builtin_amdgcn_mfma_f32_16x16x32_bf16(af, bf, acc[nt], 0, 0, 0);
      }
    }
  }
#pragma unroll
  for (int nt = 0; nt < 8; nt++) {
    int c = nt * 16 + l15;
    float b = bias[c];
#pragma unroll
    for (int r = 0; r < 4; r++)
      zb[(w * 16 + quad * 4 + r) * 132 + c] = fmaxf(acc[nt][r] + b, 0.f);
  }
  __syncthreads();
  int r = lane >> 2, seg = lane & 3;
  long grow = m0 + w * 16 + r;
  if (grow < M) {
    const float* zrow = &zb[(w * 16 + r) * 132 + seg * 32];
    const u16* ip = inp + grow * 128 + seg * 32;
    u16* op = outp + grow * 128 + seg * 32;
#pragma unroll
    for (int b = 0; b < 4; b++) {
      float zv[8];
      *(float4*)&zv[0] = *(const float4*)(zrow + b * 8);
      *(float4*)&zv[4] = *(const float4*)(zrow + b * 8 + 4);
      uint2 iv0 = *(const uint2*)(ip + b * 8);
      uint2 iv1 = *(const uint2*)(ip + b * 8 + 4);
      float i0 = bfl(iv0.x), i1 = bfh(iv0.x), i2 = bfl(iv0.y), i3 = bfh(iv0.y);
      float i4 = bfl(iv1.x), i5 = bfh(iv1.x), i6 = bfl(iv1.y), i7 = bfh(iv1.y);
      ushort4 o0 = make_ushort4(f2b(zv[0] + 0.2f * i0), f2b(zv[1] + 0.2f * i1),
                                f2b(zv[2] + 0.2f * i2), f2b(zv[3] + 0.2f * i3));
      ushort4 o1 = make_ushort4(f2b(zv[4] + 0.2f * i4), f2b(zv[5] + 0.2f * i5),
                                f2b(zv[6] + 0.2f * i6), f2b(zv[7] + 0.2f * i7));
      *(ushort4*)(op + b * 8) = o0;
      *(ushort4*)(op + b * 8 + 4) = o1;
    }
  }
}

// ------- output layer: log_softmax(mean@Wlo + blo + h@Wro), fp32 out [M,64] -------
__global__ __launch_bounds__(256) void out_mfma_k(
    const u16* __restrict__ A0, const u16* __restrict__ P0,
    const u16* __restrict__ A1, const u16* __restrict__ P1,
    const float* __restrict__ bias, float* __restrict__ outp, int M) {
  __shared__ float zb[4 * 16 * 68];
  __shared__ float rowoff[64];
  int tid = threadIdx.x;
  int w = tid >> 6, lane = tid & 63;
  int quad = lane >> 4, l15 = lane & 15;
  int m0 = blockIdx.x * 64;
  int rowa = m0 + w * 16 + l15; if (rowa > M - 1) rowa = M - 1;
  f32x4 acc[4] = {};
#pragma unroll
  for (int pass = 0; pass < 2; pass++) {
    const u16* A = pass ? A1 : A0;
    const u16* P = pass ? P1 : P0;
#pragma unroll
    for (int kt = 0; kt < 4; kt++) {
      bf16x8 af = *(const bf16x8*)(A + (long)rowa * 128 + kt * 32 + quad * 8);
      const u16* pb = P + ((kt * 4) * 64 + lane) * 8;
#pragma unroll
      for (int nt = 0; nt < 4; nt++) {
        bf16x8 bf = *(const bf16x8*)(pb + nt * 512);
        acc[nt] = __builtin_amdgcn_mfma_f32_16x16x32_bf16(af, bf, acc[nt], 0, 0, 0);
      }
    }
  }
#pragma unroll
  for (int nt = 0; nt < 4; nt++) {
    int c = nt * 16 + l15;
    float b = bias[c];
#pragma unroll
    for (int r = 0; r < 4; r++)
      zb[(w * 16 + quad * 4 + r) * 68 + c] = acc[nt][r] + b;
  }
  __syncthreads();
  if (tid < 64) {
    const float* zr = &zb[tid * 68];
    float m = -1e30f;
#pragma unroll
    for (int c = 0; c < 64; c++) m = fmaxf(m, zr[c]);
    float s = 0.f;
#pragma unroll
    for (int c = 0; c < 64; c++) s += __expf(zr[c] - m);
    rowoff[tid] = m + __logf(s);
  }
  __syncthreads();
  int r = tid >> 2, seg = tid & 3;
  long grow = m0 + r;
  if (grow < M) {
    float ro = rowoff[r];
    const float* zr = &zb[r * 68 + seg * 16];
    float* op = outp + grow * 64 + seg * 16;
#pragma unroll
    for (int b = 0; b < 4; b++) {
      float4 v = *(const float4*)(zr + b * 4);
      float4 o = make_float4(v.x - ro, v.y - ro, v.z - ro, v.w - ro);
      *(float4*)(op + b * 4) = o;
    }
  }
}

extern "C" void kernel_launch(void* const* d_in, const int* in_sizes, int n_in,
                              void* d_out, int out_size, void* d_ws, size_t ws_size,
                              hipStream_t stream) {
  if (ws_size < (size_t)WS_NEEDED) return;
  const float* x   = (const float*)d_in[0];
  const int*   ei  = (const int*)d_in[1];
  const float* Wp  = (const float*)d_in[2];
  const float* bp  = (const float*)d_in[3];
  const float* Wl  = (const float*)d_in[4];
  const float* bl  = (const float*)d_in[5];
  const float* Wr  = (const float*)d_in[6];
  const float* Wlo = (const float*)d_in[7];
  const float* blo = (const float*)d_in[8];
  const float* Wro = (const float*)d_in[9];
  float* out = (float*)d_out;
  char* ws = (char*)d_ws;
  int*   deg    = (int*)(ws + OFF_DEG);
  int*   cursor = (int*)(ws + OFF_CURSOR);
  int*   rp     = (int*)(ws + OFF_ROWPTR);
  float* invdeg = (float*)(ws + OFF_INVDEG);
  int*   col    = (int*)(ws + OFF_COL);
  int*   bsum   = (int*)(ws + OFF_COL);          // scan temps live in col pre-scatter
  int*   boff   = (int*)(ws + OFF_COL + 2048);
  u16*   pack   = (u16*)(ws + OFF_PACK);
  u16*   inp    = (u16*)(ws + OFF_INP);
  u16*   bufA   = (u16*)(ws + OFF_BUFA);
  u16*   bufB   = (u16*)(ws + OFF_BUFB);
  const int* srcv = ei;
  const int* dstv = ei + N_EDGES;

  hipMemsetAsync(ws + OFF_DEG, 0, 800000, stream);   // deg + cursor
  pack_weights_k<<<64, 256, 0, stream>>>(Wp, Wl, Wr, Wlo, Wro, pack);
  deg_hist_k<<<(N_EDGES + 255) / 256, 256, 0, stream>>>(dstv, deg);
  scan1_k<<<NB_SCAN, 256, 0, stream>>>(deg, rp, bsum);
  scan2_k<<<1, 512, 0, stream>>>(bsum, boff, rp);
  scan3_k<<<NB_SCAN, 256, 0, stream>>>(deg, boff, rp, invdeg);
  scatter_k<<<(N_EDGES + 255) / 256, 256, 0, stream>>>(srcv, dstv, rp, cursor, col);
  f2bf_k<<<12500, 256, 0, stream>>>(x, bufB, N_NODES * 32);   // xb in bufB

  int gblk = (N_NODES + 63) / 64;
  int ablk = (N_NODES + 7) / 8;

  inproj_mfma_k<<<gblk, 256, 0, stream>>>(bufB, pack + PK_WP, bp, inp, bufA, N_NODES);

  // 3 hidden SAGE layers: h lives in bufA, mean scratch in bufB; sage is row-in-place-safe
  aggregate_bf_k<<<ablk, 256, 0, stream>>>(bufA, rp, col, invdeg, bufB);
  sage_mfma_k<<<gblk, 256, 0, stream>>>(bufB, pack + PK_WL, bufA, pack + PK_WR,
                                        bl, inp, bufA, N_NODES);
  aggregate_bf_k<<<ablk, 256, 0, stream>>>(bufA, rp, col, invdeg, bufB);
  sage_mfma_k<<<gblk, 256, 0, stream>>>(bufB, pack + PK_WL + 16384, bufA, pack + PK_WR + 16384,
                                        bl + 128, inp, bufA, N_NODES);
  aggregate_bf_k<<<ablk, 256, 0, stream>>>(bufA, rp, col, invdeg, bufB);
  sage_mfma_k<<<gblk, 256, 0, stream>>>(bufB, pack + PK_WL + 32768, bufA, pack + PK_WR + 32768,
                                        bl + 256, inp, bufA, N_NODES);
  // output layer + log_softmax
  aggregate_bf_k<<<ablk, 256, 0, stream>>>(bufA, rp, col, invdeg, bufB);
  out_mfma_k<<<gblk, 256, 0, stream>>>(bufB, pack + PK_WLO, bufA, pack + PK_WRO,
                                       blo, out, N_NODES);
}

// Round 4
// 683.152 us; speedup vs baseline: 2.1251x; 1.2740x over previous
//
#include <hip/hip_runtime.h>
#include <math.h>

#define N_NODES 100000
#define N_EDGES 1600000
#define NBUK 391          // ceil(N/256) buckets of 256 consecutive dst nodes
#define PCHUNK 8192       // edges per partition block
#define NPBLK 196         // ceil(E/PCHUNK)

typedef unsigned short u16;
typedef __bf16 bf16x8 __attribute__((ext_vector_type(8)));
typedef float f32x4 __attribute__((ext_vector_type(4)));

// ---- workspace layout (bytes), 16B-aligned ----
#define OFF_RP      0u          // int[N+1]
#define OFF_INVDEG  400016u     // float[N]
#define OFF_BHIST   800016u     // int[392]
#define OFF_BBASE   801600u     // int[392]
#define OFF_GCUR    803200u     // int[392]
#define OFF_PAIRS   804800u     // uint2[E] = 12.8 MB
#define OFF_COL     13604800u   // int[E]
#define OFF_PACK    20004800u   // u16[131072] packed bf16 weight fragments
#define OFF_INP     20266944u   // u16[N*128] residual, bf16
#define OFF_BUFA    45866944u   // u16[N*128] h, bf16
#define OFF_BUFB    71466944u   // u16[N*128] mean scratch, bf16
#define WS_NEEDED   97066944u

// packed-weight element offsets (u16 units)
#define PK_WP   0
#define PK_WL   16384
#define PK_WR   65536
#define PK_WLO  114688
#define PK_WRO  122880

__device__ __forceinline__ float bfl(unsigned u) {
  union { unsigned i; float f; } v; v.i = u << 16; return v.f;
}
__device__ __forceinline__ float bfh(unsigned u) {
  union { unsigned i; float f; } v; v.i = u & 0xFFFF0000u; return v.f;
}
__device__ __forceinline__ u16 f2b(float f) {       // RTNE
  union { float f; unsigned i; } v; v.f = f;
  unsigned r = (v.i + 0x7FFFu + ((v.i >> 16) & 1u)) >> 16;
  return (u16)r;
}

// ---------------- pack fp32 weights -> bf16 MFMA B-fragments ----------------
__global__ __launch_bounds__(256) void pack_weights_k(
    const float* __restrict__ Wp, const float* __restrict__ Wl,
    const float* __restrict__ Wr, const float* __restrict__ Wlo,
    const float* __restrict__ Wro, u16* __restrict__ P) {
  int t = blockIdx.x * 256 + threadIdx.x;
  if (t >= 16384) return;
  const float* W; u16* dst; int j; int NT;
  if (t < 2048)        { W = Wp;                    dst = P + PK_WP;                j = t;                 NT = 8; }
  else if (t < 8192)   { int m = (t - 2048) >> 11;  j = (t - 2048) & 2047;
                         W = Wl + (m << 14);        dst = P + PK_WL + (m << 14);    NT = 8; }
  else if (t < 14336)  { int m = (t - 8192) >> 11;  j = (t - 8192) & 2047;
                         W = Wr + (m << 14);        dst = P + PK_WR + (m << 14);    NT = 8; }
  else if (t < 15360)  { j = t - 14336;             W = Wlo;  dst = P + PK_WLO;     NT = 4; }
  else                 { j = t - 15360;             W = Wro;  dst = P + PK_WRO;     NT = 4; }
  int lane = j & 63;
  int nt, kt;
  if (NT == 8) { nt = (j >> 6) & 7; kt = j >> 9; }
  else         { nt = (j >> 6) & 3; kt = j >> 8; }
  int n  = nt * 16 + (lane & 15);
  int k0 = kt * 32 + ((lane >> 4) << 3);
  const float* s = W + n * 128 + k0;
  ushort4 lo = make_ushort4(f2b(s[0]), f2b(s[1]), f2b(s[2]), f2b(s[3]));
  ushort4 hi = make_ushort4(f2b(s[4]), f2b(s[5]), f2b(s[6]), f2b(s[7]));
  *(ushort4*)(dst + j * 8)     = lo;
  *(ushort4*)(dst + j * 8 + 4) = hi;
}

// ---------- bucket histogram: LDS per-block, merge to global ----------
__global__ __launch_bounds__(256) void bhist_k(const int* __restrict__ dst,
                                               int* __restrict__ bhist) {
  __shared__ int lc[NBUK];
  int t = threadIdx.x;
  for (int i = t; i < NBUK; i += 256) lc[i] = 0;
  __syncthreads();
  int base = blockIdx.x * 4096;
#pragma unroll
  for (int r = 0; r < 16; r++) {
    int i = base + r * 256 + t;
    if (i < N_EDGES) atomicAdd(&lc[dst[i] >> 8], 1);
  }
  __syncthreads();
  for (int i = t; i < NBUK; i += 256)
    if (lc[i]) atomicAdd(&bhist[i], lc[i]);
}

// ---------- single-block scan of bucket counts ----------
__global__ __launch_bounds__(512) void bscan_k(const int* __restrict__ bhist,
                                               int* __restrict__ bbase,
                                               int* __restrict__ gcur,
                                               int* __restrict__ rp) {
  __shared__ int s[512];
  int t = threadIdx.x;
  int v = (t < NBUK) ? bhist[t] : 0;
  s[t] = v;
  __syncthreads();
  for (int off = 1; off < 512; off <<= 1) {
    int u = (t >= off) ? s[t - off] : 0;
    __syncthreads();
    s[t] += u;
    __syncthreads();
  }
  if (t < NBUK) { int e = s[t] - v; bbase[t] = e; gcur[t] = e; }
  if (t == NBUK - 1) { bbase[NBUK] = s[t]; rp[N_NODES] = s[t]; }
}

// ---------- partition edges into bucket-contiguous (src,dst) pairs ----------
__global__ __launch_bounds__(256) void part_k(const int* __restrict__ src,
                                              const int* __restrict__ dst,
                                              int* __restrict__ gcur,
                                              uint2* __restrict__ pairs) {
  __shared__ int lcnt[NBUK + 1];
  __shared__ int lofs[512];
  __shared__ int cur[NBUK];
  __shared__ int gslot[NBUK];
  __shared__ uint2 stag[PCHUNK];
  int t = threadIdx.x;
  for (int i = t; i < NBUK + 1; i += 256) lcnt[i] = 0;
  __syncthreads();
  int base = blockIdx.x * PCHUNK;
  // pass 1: count
#pragma unroll
  for (int r = 0; r < PCHUNK / 256; r++) {
    int i = base + r * 256 + t;
    if (i < N_EDGES) atomicAdd(&lcnt[dst[i] >> 8], 1);
  }
  __syncthreads();
  // exclusive scan of lcnt[0..391] over padded 512 (2 elems/thread)
  {
    int e1 = t + 256;
    lofs[t]  = (t  <= NBUK) ? lcnt[t]  : 0;
    lofs[e1] = (e1 <= NBUK) ? lcnt[e1] : 0;
    __syncthreads();
    for (int off = 1; off < 512; off <<= 1) {
      int a0 = (t  >= off) ? lofs[t  - off] : 0;
      int a1 = (e1 >= off) ? lofs[e1 - off] : 0;
      __syncthreads();
      lofs[t] += a0; lofs[e1] += a1;
      __syncthreads();
    }
    // convert inclusive -> exclusive in place (shift by own count)
    int o0 = lofs[t]  - ((t  <= NBUK) ? lcnt[t]  : 0);
    int o1 = lofs[e1] - ((e1 <= NBUK) ? lcnt[e1] : 0);
    __syncthreads();
    lofs[t] = o0; lofs[e1] = o1;
    __syncthreads();
  }
  for (int i = t; i < NBUK; i += 256) cur[i] = lofs[i];
  __syncthreads();
  // pass 2: stage bucket-sorted
#pragma unroll
  for (int r = 0; r < PCHUNK / 256; r++) {
    int i = base + r * 256 + t;
    if (i < N_EDGES) {
      int d = dst[i];
      int slot = atomicAdd(&cur[d >> 8], 1);
      stag[slot] = make_uint2((unsigned)src[i], (unsigned)d);
    }
  }
  __syncthreads();
  // reserve global space per bucket
  for (int i = t; i < NBUK; i += 256)
    if (lcnt[i]) gslot[i] = atomicAdd(&gcur[i], lcnt[i]);
  __syncthreads();
  // pass 3: copy out (bucket-sorted -> mostly-coalesced runs)
  int total = lofs[NBUK];
  for (int p = t; p < total; p += 256) {
    uint2 pr = stag[p];
    int b = (int)(pr.y >> 8);
    pairs[gslot[b] + (p - lofs[b])] = pr;
  }
}

// ---------- per-bucket CSR finalize: rp, invdeg, col ----------
__global__ __launch_bounds__(256) void csr_k(const uint2* __restrict__ pairs,
                                             const int* __restrict__ bbase,
                                             int* __restrict__ rp,
                                             float* __restrict__ invdeg,
                                             int* __restrict__ col) {
  __shared__ int cnt[256];
  __shared__ int scn[256];
  __shared__ int cur[256];
  int b = blockIdx.x, t = threadIdx.x;
  int lo = bbase[b], hi = bbase[b + 1];
  cnt[t] = 0;
  __syncthreads();
  for (int p = lo + t; p < hi; p += 256)
    atomicAdd(&cnt[pairs[p].y & 255], 1);
  __syncthreads();
  int c = cnt[t];
  scn[t] = c;
  __syncthreads();
  for (int off = 1; off < 256; off <<= 1) {
    int v = (t >= off) ? scn[t - off] : 0;
    __syncthreads();
    scn[t] += v;
    __syncthreads();
  }
  int excl = scn[t] - c;
  int node = (b << 8) + t;
  if (node < N_NODES) {
    rp[node] = lo + excl;
    invdeg[node] = 1.0f / (float)(c > 1 ? c : 1);
  }
  cur[t] = lo + excl;
  __syncthreads();
  for (int p = lo + t; p < hi; p += 256) {
    uint2 pr = pairs[p];
    int slot = atomicAdd(&cur[pr.y & 255], 1);
    col[slot] = (int)pr.x;
  }
}

// ------- mean aggregation (bf16 rows): half-wave per node, 8B loads, x4 unroll -------
__global__ __launch_bounds__(256) void aggregate_bf_k(const u16* __restrict__ h,
                                                      const int* __restrict__ rp,
                                                      const int* __restrict__ col,
                                                      const float* __restrict__ invdeg,
                                                      u16* __restrict__ mean) {
  int node = blockIdx.x * 8 + (threadIdx.x >> 5);
  int lane = threadIdx.x & 31;
  if (node >= N_NODES) return;
  int beg = rp[node], end = rp[node + 1];
  const u16* hp = h + lane * 4;
  float a0 = 0.f, a1 = 0.f, a2 = 0.f, a3 = 0.f;
  int j = beg;
  for (; j + 3 < end; j += 4) {
    int s0 = col[j], s1 = col[j + 1], s2 = col[j + 2], s3 = col[j + 3];
    uint2 v0 = *(const uint2*)(hp + ((long)s0 << 7));
    uint2 v1 = *(const uint2*)(hp + ((long)s1 << 7));
    uint2 v2 = *(const uint2*)(hp + ((long)s2 << 7));
    uint2 v3 = *(const uint2*)(hp + ((long)s3 << 7));
    a0 += (bfl(v0.x) + bfl(v1.x)) + (bfl(v2.x) + bfl(v3.x));
    a1 += (bfh(v0.x) + bfh(v1.x)) + (bfh(v2.x) + bfh(v3.x));
    a2 += (bfl(v0.y) + bfl(v1.y)) + (bfl(v2.y) + bfl(v3.y));
    a3 += (bfh(v0.y) + bfh(v1.y)) + (bfh(v2.y) + bfh(v3.y));
  }
  for (; j < end; j++) {
    uint2 v0 = *(const uint2*)(hp + ((long)col[j] << 7));
    a0 += bfl(v0.x); a1 += bfh(v0.x); a2 += bfl(v0.y); a3 += bfh(v0.y);
  }
  float w = invdeg[node];
  ushort4 r = make_ushort4(f2b(a0 * w), f2b(a1 * w), f2b(a2 * w), f2b(a3 * w));
  *(ushort4*)(mean + ((long)node << 7) + lane * 4) = r;
}

// ======== MFMA GEMM family ========
// a_frag: A[m=lane&15][k=quad*8+j]; b_frag: packed P; C/D: row=quad*4+reg, col=nt*16+(lane&15)

// ------- inProj (fused fp32->bf16): z = x@WpT + bp; inp=bf16(z); hA=bf16(relu(z)) -------
__global__ __launch_bounds__(256) void inproj_mfma_k(
    const float* __restrict__ X, const u16* __restrict__ P,
    const float* __restrict__ bias,
    u16* __restrict__ inp, u16* __restrict__ hout, int M) {
  __shared__ float zb[4 * 16 * 132];
  int tid = threadIdx.x;
  int w = tid >> 6, lane = tid & 63;
  int quad = lane >> 4, l15 = lane & 15;
  int m0 = blockIdx.x * 64;
  int rowa = m0 + w * 16 + l15; if (rowa > M - 1) rowa = M - 1;
  f32x4 acc[8] = {};
#pragma unroll
  for (int kt = 0; kt < 4; kt++) {
    const float* xr = X + (long)rowa * 128 + kt * 32 + quad * 8;
    float4 p0 = *(const float4*)xr;
    float4 p1 = *(const float4*)(xr + 4);
    union { ushort4 u4[2]; bf16x8 v; } fa;
    fa.u4[0] = make_ushort4(f2b(p0.x), f2b(p0.y), f2b(p0.z), f2b(p0.w));
    fa.u4[1] = make_ushort4(f2b(p1.x), f2b(p1.y), f2b(p1.z), f2b(p1.w));
    const u16* pb = P + ((kt * 8) * 64 + lane) * 8;
#pragma unroll
    for (int nt = 0; nt < 8; nt++) {
      bf16x8 bf = *(const bf16x8*)(pb + nt * 512);
      acc[nt] = __builtin_amdgcn_mfma_f32_16x16x32_bf16(fa.v, bf, acc[nt], 0, 0, 0);
    }
  }
#pragma unroll
  for (int nt = 0; nt < 8; nt++) {
    int c = nt * 16 + l15;
    float b = bias[c];
#pragma unroll
    for (int r = 0; r < 4; r++)
      zb[(w * 16 + quad * 4 + r) * 132 + c] = acc[nt][r] + b;
  }
  __syncthreads();
  int r = lane >> 2, seg = lane & 3;
  long grow = m0 + w * 16 + r;
  if (grow < M) {
    const float* zrow = &zb[(w * 16 + r) * 132 + seg * 32];
    u16* ip = inp + grow * 128 + seg * 32;
    u16* hp = hout + grow * 128 + seg * 32;
#pragma unroll
    for (int b = 0; b < 4; b++) {
      float zv[8];
      *(float4*)&zv[0] = *(const float4*)(zrow + b * 8);
      *(float4*)&zv[4] = *(const float4*)(zrow + b * 8 + 4);
      ushort4 o0 = make_ushort4(f2b(zv[0]), f2b(zv[1]), f2b(zv[2]), f2b(zv[3]));
      ushort4 o1 = make_ushort4(f2b(zv[4]), f2b(zv[5]), f2b(zv[6]), f2b(zv[7]));
      ushort4 r0 = make_ushort4(f2b(fmaxf(zv[0], 0.f)), f2b(fmaxf(zv[1], 0.f)),
                                f2b(fmaxf(zv[2], 0.f)), f2b(fmaxf(zv[3], 0.f)));
      ushort4 r1 = make_ushort4(f2b(fmaxf(zv[4], 0.f)), f2b(fmaxf(zv[5], 0.f)),
                                f2b(fmaxf(zv[6], 0.f)), f2b(fmaxf(zv[7], 0.f)));
      *(ushort4*)(ip + b * 8) = o0; *(ushort4*)(ip + b * 8 + 4) = o1;
      *(ushort4*)(hp + b * 8) = r0; *(ushort4*)(hp + b * 8 + 4) = r1;
    }
  }
}

// ------- SAGE layer: h = bf16(relu(mean@Wl + bl + h@Wr) + 0.2*inp), in-place on A1 -------
__global__ __launch_bounds__(256) void sage_mfma_k(
    const u16* __restrict__ A0, const u16* __restrict__ P0,
    const u16* __restrict__ A1, const u16* __restrict__ P1,
    const float* __restrict__ bias, const u16* __restrict__ inp,
    u16* __restrict__ outp, int M) {
  __shared__ float zb[4 * 16 * 132];
  int tid = threadIdx.x;
  int w = tid >> 6, lane = tid & 63;
  int quad = lane >> 4, l15 = lane & 15;
  int m0 = blockIdx.x * 64;
  int rowa = m0 + w * 16 + l15; if (rowa > M - 1) rowa = M - 1;
  f32x4 acc[8] = {};
#pragma unroll
  for (int pass = 0; pass < 2; pass++) {
    const u16* A = pass ? A1 : A0;
    const u16* P = pass ? P1 : P0;
#pragma unroll
    for (int kt = 0; kt < 4; kt++) {
      bf16x8 af = *(const bf16x8*)(A + (long)rowa * 128 + kt * 32 + quad * 8);
      const u16* pb = P + ((kt * 8) * 64 + lane) * 8;
#pragma unroll
      for (int nt = 0; nt < 8; nt++) {
        bf16x8 bf = *(const bf16x8*)(pb + nt * 512);
        acc[nt] = __builtin_amdgcn_mfma_f32_16x16x32_bf16(af, bf, acc[nt], 0, 0, 0);
      }
    }
  }
#pragma unroll
  for (int nt = 0; nt < 8; nt++) {
    int c = nt * 16 + l15;
    float b = bias[c];
#pragma unroll
    for (int r = 0; r < 4; r++)
      zb[(w * 16 + quad * 4 + r) * 132 + c] = fmaxf(acc[nt][r] + b, 0.f);
  }
  __syncthreads();
  int r = lane >> 2, seg = lane & 3;
  long grow = m0 + w * 16 + r;
  if (grow < M) {
    const float* zrow = &zb[(w * 16 + r) * 132 + seg * 32];
    const u16* ip = inp + grow * 128 + seg * 32;
    u16* op = outp + grow * 128 + seg * 32;
#pragma unroll
    for (int b = 0; b < 4; b++) {
      float zv[8];
      *(float4*)&zv[0] = *(const float4*)(zrow + b * 8);
      *(float4*)&zv[4] = *(const float4*)(zrow + b * 8 + 4);
      uint2 iv0 = *(const uint2*)(ip + b * 8);
      uint2 iv1 = *(const uint2*)(ip + b * 8 + 4);
      float i0 = bfl(iv0.x), i1 = bfh(iv0.x), i2 = bfl(iv0.y), i3 = bfh(iv0.y);
      float i4 = bfl(iv1.x), i5 = bfh(iv1.x), i6 = bfl(iv1.y), i7 = bfh(iv1.y);
      ushort4 o0 = make_ushort4(f2b(zv[0] + 0.2f * i0), f2b(zv[1] + 0.2f * i1),
                                f2b(zv[2] + 0.2f * i2), f2b(zv[3] + 0.2f * i3));
      ushort4 o1 = make_ushort4(f2b(zv[4] + 0.2f * i4), f2b(zv[5] + 0.2f * i5),
                                f2b(zv[6] + 0.2f * i6), f2b(zv[7] + 0.2f * i7));
      *(ushort4*)(op + b * 8) = o0;
      *(ushort4*)(op + b * 8 + 4) = o1;
    }
  }
}

// ------- output layer: log_softmax(mean@Wlo + blo + h@Wro), fp32 out [M,64] -------
__global__ __launch_bounds__(256) void out_mfma_k(
    const u16* __restrict__ A0, const u16* __restrict__ P0,
    const u16* __restrict__ A1, const u16* __restrict__ P1,
    const float* __restrict__ bias, float* __restrict__ outp, int M) {
  __shared__ float zb[4 * 16 * 68];
  __shared__ float rowoff[64];
  int tid = threadIdx.x;
  int w = tid >> 6, lane = tid & 63;
  int quad = lane >> 4, l15 = lane & 15;
  int m0 = blockIdx.x * 64;
  int rowa = m0 + w * 16 + l15; if (rowa > M - 1) rowa = M - 1;
  f32x4 acc[4] = {};
#pragma unroll
  for (int pass = 0; pass < 2; pass++) {
    const u16* A = pass ? A1 : A0;
    const u16* P = pass ? P1 : P0;
#pragma unroll
    for (int kt = 0; kt < 4; kt++) {
      bf16x8 af = *(const bf16x8*)(A + (long)rowa * 128 + kt * 32 + quad * 8);
      const u16* pb = P + ((kt * 4) * 64 + lane) * 8;
#pragma unroll
      for (int nt = 0; nt < 4; nt++) {
        bf16x8 bf = *(const bf16x8*)(pb + nt * 512);
        acc[nt] = __builtin_amdgcn_mfma_f32_16x16x32_bf16(af, bf, acc[nt], 0, 0, 0);
      }
    }
  }
#pragma unroll
  for (int nt = 0; nt < 4; nt++) {
    int c = nt * 16 + l15;
    float b = bias[c];
#pragma unroll
    for (int r = 0; r < 4; r++)
      zb[(w * 16 + quad * 4 + r) * 68 + c] = acc[nt][r] + b;
  }
  __syncthreads();
  if (tid < 64) {
    const float* zr = &zb[tid * 68];
    float m = -1e30f;
#pragma unroll
    for (int c = 0; c < 64; c++) m = fmaxf(m, zr[c]);
    float s = 0.f;
#pragma unroll
    for (int c = 0; c < 64; c++) s += __expf(zr[c] - m);
    rowoff[tid] = m + __logf(s);
  }
  __syncthreads();
  int r = tid >> 2, seg = tid & 3;
  long grow = m0 + r;
  if (grow < M) {
    float ro = rowoff[r];
    const float* zr = &zb[r * 68 + seg * 16];
    float* op = outp + grow * 64 + seg * 16;
#pragma unroll
    for (int b = 0; b < 4; b++) {
      float4 v = *(const float4*)(zr + b * 4);
      float4 o = make_float4(v.x - ro, v.y - ro, v.z - ro, v.w - ro);
      *(float4*)(op + b * 4) = o;
    }
  }
}

extern "C" void kernel_launch(void* const* d_in, const int* in_sizes, int n_in,
                              void* d_out, int out_size, void* d_ws, size_t ws_size,
                              hipStream_t stream) {
  if (ws_size < (size_t)WS_NEEDED) return;
  const float* x   = (const float*)d_in[0];
  const int*   ei  = (const int*)d_in[1];
  const float* Wp  = (const float*)d_in[2];
  const float* bp  = (const float*)d_in[3];
  const float* Wl  = (const float*)d_in[4];
  const float* bl  = (const float*)d_in[5];
  const float* Wr  = (const float*)d_in[6];
  const float* Wlo = (const float*)d_in[7];
  const float* blo = (const float*)d_in[8];
  const float* Wro = (const float*)d_in[9];
  float* out = (float*)d_out;
  char* ws = (char*)d_ws;
  int*   rp     = (int*)(ws + OFF_RP);
  float* invdeg = (float*)(ws + OFF_INVDEG);
  int*   bhist  = (int*)(ws + OFF_BHIST);
  int*   bbase  = (int*)(ws + OFF_BBASE);
  int*   gcur   = (int*)(ws + OFF_GCUR);
  uint2* pairs  = (uint2*)(ws + OFF_PAIRS);
  int*   col    = (int*)(ws + OFF_COL);
  u16*   pack   = (u16*)(ws + OFF_PACK);
  u16*   inp    = (u16*)(ws + OFF_INP);
  u16*   bufA   = (u16*)(ws + OFF_BUFA);
  u16*   bufB   = (u16*)(ws + OFF_BUFB);
  const int* srcv = ei;
  const int* dstv = ei + N_EDGES;

  hipMemsetAsync(ws + OFF_BHIST, 0, (NBUK + 1) * 4, stream);
  pack_weights_k<<<64, 256, 0, stream>>>(Wp, Wl, Wr, Wlo, Wro, pack);
  bhist_k<<<391, 256, 0, stream>>>(dstv, bhist);
  bscan_k<<<1, 512, 0, stream>>>(bhist, bbase, gcur, rp);
  part_k<<<NPBLK, 256, 0, stream>>>(srcv, dstv, gcur, pairs);
  csr_k<<<NBUK, 256, 0, stream>>>(pairs, bbase, rp, invdeg, col);

  int gblk = (N_NODES + 63) / 64;
  int ablk = (N_NODES + 7) / 8;

  inproj_mfma_k<<<gblk, 256, 0, stream>>>(x, pack + PK_WP, bp, inp, bufA, N_NODES);

  aggregate_bf_k<<<ablk, 256, 0, stream>>>(bufA, rp, col, invdeg, bufB);
  sage_mfma_k<<<gblk, 256, 0, stream>>>(bufB, pack + PK_WL, bufA, pack + PK_WR,
                                        bl, inp, bufA, N_NODES);
  aggregate_bf_k<<<ablk, 256, 0, stream>>>(bufA, rp, col, invdeg, bufB);
  sage_mfma_k<<<gblk, 256, 0, stream>>>(bufB, pack + PK_WL + 16384, bufA, pack + PK_WR + 16384,
                                        bl + 128, inp, bufA, N_NODES);
  aggregate_bf_k<<<ablk, 256, 0, stream>>>(bufA, rp, col, invdeg, bufB);
  sage_mfma_k<<<gblk, 256, 0, stream>>>(bufB, pack + PK_WL + 32768, bufA, pack + PK_WR + 32768,
                                        bl + 256, inp, bufA, N_NODES);
  aggregate_bf_k<<<ablk, 256, 0, stream>>>(bufA, rp, col, invdeg, bufB);
  out_mfma_k<<<gblk, 256, 0, stream>>>(bufB, pack + PK_WLO, bufA, pack + PK_WRO,
                                       blo, out, N_NODES);
}

// Round 5
// 615.509 us; speedup vs baseline: 2.3586x; 1.1099x over previous
//
#include <hip/hip_runtime.h>
#include <math.h>

#define N_NODES 100000
#define N_EDGES 1600000
#define NBUK 391          // ceil(N/256) buckets of 256 consecutive dst nodes
#define PCHUNK 8192       // edges per partition block
#define NPBLK 196         // ceil(E/PCHUNK)

typedef unsigned short u16;
typedef unsigned char u8;
typedef __bf16 bf16x8 __attribute__((ext_vector_type(8)));
typedef float f32x4 __attribute__((ext_vector_type(4)));
typedef float f32x2 __attribute__((ext_vector_type(2)));

// ---- workspace layout (bytes), 16B-aligned ----
#define OFF_RP      0u          // int[N+1]
#define OFF_INVDEG  400016u     // float[N]
#define OFF_BHIST   800016u     // int[392]
#define OFF_BBASE   801600u     // int[392]
#define OFF_GCUR    803200u     // int[392]
#define OFF_PAIRS   804800u     // uint2[E] = 12.8 MB
#define OFF_COL     13604800u   // int[E]
#define OFF_PACK    20004800u   // u16[131072] packed bf16 weight fragments
#define OFF_INP     20266944u   // u16[N*128] residual (pre-relu inProj), bf16
#define OFF_H       45866944u   // u16[N*128] h (in-place across layers), bf16
#define OFF_H8A     71466944u   // u8[N*128] fp8 copy of h (gather path), buffer A
#define OFF_H8B     84266944u   // u8[N*128] fp8 copy, buffer B
#define OFF_GL      97066944u   // u16[N*64] projected neighbor logits, bf16
#define OFF_GR      109866944u  // u16[N*64] projected root logits, bf16
#define WS_NEEDED   122666944u

// packed-weight element offsets (u16 units)
#define PK_WP   0
#define PK_WL   16384
#define PK_WR   65536
#define PK_WLO  114688
#define PK_WRO  122880

__device__ __forceinline__ float bfl(unsigned u) {
  union { unsigned i; float f; } v; v.i = u << 16; return v.f;
}
__device__ __forceinline__ float bfh(unsigned u) {
  union { unsigned i; float f; } v; v.i = u & 0xFFFF0000u; return v.f;
}
__device__ __forceinline__ u16 f2b(float f) {       // RTNE
  union { float f; unsigned i; } v; v.f = f;
  unsigned r = (v.i + 0x7FFFu + ((v.i >> 16) & 1u)) >> 16;
  return (u16)r;
}

// ---------------- pack fp32 weights -> bf16 MFMA B-fragments ----------------
__global__ __launch_bounds__(256) void pack_weights_k(
    const float* __restrict__ Wp, const float* __restrict__ Wl,
    const float* __restrict__ Wr, const float* __restrict__ Wlo,
    const float* __restrict__ Wro, u16* __restrict__ P) {
  int t = blockIdx.x * 256 + threadIdx.x;
  if (t >= 16384) return;
  const float* W; u16* dst; int j; int NT;
  if (t < 2048)        { W = Wp;                    dst = P + PK_WP;                j = t;                 NT = 8; }
  else if (t < 8192)   { int m = (t - 2048) >> 11;  j = (t - 2048) & 2047;
                         W = Wl + (m << 14);        dst = P + PK_WL + (m << 14);    NT = 8; }
  else if (t < 14336)  { int m = (t - 8192) >> 11;  j = (t - 8192) & 2047;
                         W = Wr + (m << 14);        dst = P + PK_WR + (m << 14);    NT = 8; }
  else if (t < 15360)  { j = t - 14336;             W = Wlo;  dst = P + PK_WLO;     NT = 4; }
  else                 { j = t - 15360;             W = Wro;  dst = P + PK_WRO;     NT = 4; }
  int lane = j & 63;
  int nt, kt;
  if (NT == 8) { nt = (j >> 6) & 7; kt = j >> 9; }
  else         { nt = (j >> 6) & 3; kt = j >> 8; }
  int n  = nt * 16 + (lane & 15);
  int k0 = kt * 32 + ((lane >> 4) << 3);
  const float* s = W + n * 128 + k0;
  ushort4 lo = make_ushort4(f2b(s[0]), f2b(s[1]), f2b(s[2]), f2b(s[3]));
  ushort4 hi = make_ushort4(f2b(s[4]), f2b(s[5]), f2b(s[6]), f2b(s[7]));
  *(ushort4*)(dst + j * 8)     = lo;
  *(ushort4*)(dst + j * 8 + 4) = hi;
}

// ---------- bucket histogram ----------
__global__ __launch_bounds__(256) void bhist_k(const int* __restrict__ dst,
                                               int* __restrict__ bhist) {
  __shared__ int lc[NBUK];
  int t = threadIdx.x;
  for (int i = t; i < NBUK; i += 256) lc[i] = 0;
  __syncthreads();
  int base = blockIdx.x * 4096;
#pragma unroll
  for (int r = 0; r < 16; r++) {
    int i = base + r * 256 + t;
    if (i < N_EDGES) atomicAdd(&lc[dst[i] >> 8], 1);
  }
  __syncthreads();
  for (int i = t; i < NBUK; i += 256)
    if (lc[i]) atomicAdd(&bhist[i], lc[i]);
}

// ---------- single-block scan of bucket counts ----------
__global__ __launch_bounds__(512) void bscan_k(const int* __restrict__ bhist,
                                               int* __restrict__ bbase,
                                               int* __restrict__ gcur,
                                               int* __restrict__ rp) {
  __shared__ int s[512];
  int t = threadIdx.x;
  int v = (t < NBUK) ? bhist[t] : 0;
  s[t] = v;
  __syncthreads();
  for (int off = 1; off < 512; off <<= 1) {
    int u = (t >= off) ? s[t - off] : 0;
    __syncthreads();
    s[t] += u;
    __syncthreads();
  }
  if (t < NBUK) { int e = s[t] - v; bbase[t] = e; gcur[t] = e; }
  if (t == NBUK - 1) { bbase[NBUK] = s[t]; rp[N_NODES] = s[t]; }
}

// ---------- partition edges into bucket-contiguous (src,dst) pairs ----------
__global__ __launch_bounds__(256) void part_k(const int* __restrict__ src,
                                              const int* __restrict__ dst,
                                              int* __restrict__ gcur,
                                              uint2* __restrict__ pairs) {
  __shared__ int lcnt[NBUK + 1];
  __shared__ int lofs[512];
  __shared__ int cur[NBUK];
  __shared__ int gslot[NBUK];
  __shared__ uint2 stag[PCHUNK];
  int t = threadIdx.x;
  for (int i = t; i < NBUK + 1; i += 256) lcnt[i] = 0;
  __syncthreads();
  int base = blockIdx.x * PCHUNK;
#pragma unroll
  for (int r = 0; r < PCHUNK / 256; r++) {
    int i = base + r * 256 + t;
    if (i < N_EDGES) atomicAdd(&lcnt[dst[i] >> 8], 1);
  }
  __syncthreads();
  {
    int e1 = t + 256;
    lofs[t]  = (t  <= NBUK) ? lcnt[t]  : 0;
    lofs[e1] = (e1 <= NBUK) ? lcnt[e1] : 0;
    __syncthreads();
    for (int off = 1; off < 512; off <<= 1) {
      int a0 = (t  >= off) ? lofs[t  - off] : 0;
      int a1 = (e1 >= off) ? lofs[e1 - off] : 0;
      __syncthreads();
      lofs[t] += a0; lofs[e1] += a1;
      __syncthreads();
    }
    int o0 = lofs[t]  - ((t  <= NBUK) ? lcnt[t]  : 0);
    int o1 = lofs[e1] - ((e1 <= NBUK) ? lcnt[e1] : 0);
    __syncthreads();
    lofs[t] = o0; lofs[e1] = o1;
    __syncthreads();
  }
  for (int i = t; i < NBUK; i += 256) cur[i] = lofs[i];
  __syncthreads();
#pragma unroll
  for (int r = 0; r < PCHUNK / 256; r++) {
    int i = base + r * 256 + t;
    if (i < N_EDGES) {
      int d = dst[i];
      int slot = atomicAdd(&cur[d >> 8], 1);
      stag[slot] = make_uint2((unsigned)src[i], (unsigned)d);
    }
  }
  __syncthreads();
  for (int i = t; i < NBUK; i += 256)
    if (lcnt[i]) gslot[i] = atomicAdd(&gcur[i], lcnt[i]);
  __syncthreads();
  int total = lofs[NBUK];
  for (int p = t; p < total; p += 256) {
    uint2 pr = stag[p];
    int b = (int)(pr.y >> 8);
    pairs[gslot[b] + (p - lofs[b])] = pr;
  }
}

// ---------- per-bucket CSR finalize ----------
__global__ __launch_bounds__(256) void csr_k(const uint2* __restrict__ pairs,
                                             const int* __restrict__ bbase,
                                             int* __restrict__ rp,
                                             float* __restrict__ invdeg,
                                             int* __restrict__ col) {
  __shared__ int cnt[256];
  __shared__ int scn[256];
  __shared__ int cur[256];
  int b = blockIdx.x, t = threadIdx.x;
  int lo = bbase[b], hi = bbase[b + 1];
  cnt[t] = 0;
  __syncthreads();
  for (int p = lo + t; p < hi; p += 256)
    atomicAdd(&cnt[pairs[p].y & 255], 1);
  __syncthreads();
  int c = cnt[t];
  scn[t] = c;
  __syncthreads();
  for (int off = 1; off < 256; off <<= 1) {
    int v = (t >= off) ? scn[t - off] : 0;
    __syncthreads();
    scn[t] += v;
    __syncthreads();
  }
  int excl = scn[t] - c;
  int node = (b << 8) + t;
  if (node < N_NODES) {
    rp[node] = lo + excl;
    invdeg[node] = 1.0f / (float)(c > 1 ? c : 1);
  }
  cur[t] = lo + excl;
  __syncthreads();
  for (int p = lo + t; p < hi; p += 256) {
    uint2 pr = pairs[p];
    int slot = atomicAdd(&cur[pr.y & 255], 1);
    col[slot] = (int)pr.x;
  }
}

// ------- inProj: z = x@WpT + bp; inp=bf16(z); h=bf16(relu(z)); h8=fp8(relu(z)) -------
__global__ __launch_bounds__(256) void inproj_mfma_k(
    const float* __restrict__ X, const u16* __restrict__ P,
    const float* __restrict__ bias,
    u16* __restrict__ inp, u16* __restrict__ hout, u8* __restrict__ h8out, int M) {
  __shared__ float zb[64 * 132];
  int tid = threadIdx.x;
  int w = tid >> 6, lane = tid & 63;
  int quad = lane >> 4, l15 = lane & 15;
  int m0 = blockIdx.x * 64;
  int rowa = m0 + w * 16 + l15; if (rowa > M - 1) rowa = M - 1;
  f32x4 acc[8] = {};
#pragma unroll
  for (int kt = 0; kt < 4; kt++) {
    const float* xr = X + (long)rowa * 128 + kt * 32 + quad * 8;
    float4 p0 = *(const float4*)xr;
    float4 p1 = *(const float4*)(xr + 4);
    union { ushort4 u4[2]; bf16x8 v; } fa;
    fa.u4[0] = make_ushort4(f2b(p0.x), f2b(p0.y), f2b(p0.z), f2b(p0.w));
    fa.u4[1] = make_ushort4(f2b(p1.x), f2b(p1.y), f2b(p1.z), f2b(p1.w));
    const u16* pb = P + ((kt * 8) * 64 + lane) * 8;
#pragma unroll
    for (int nt = 0; nt < 8; nt++) {
      bf16x8 bf = *(const bf16x8*)(pb + nt * 512);
      acc[nt] = __builtin_amdgcn_mfma_f32_16x16x32_bf16(fa.v, bf, acc[nt], 0, 0, 0);
    }
  }
#pragma unroll
  for (int nt = 0; nt < 8; nt++) {
    int c = nt * 16 + l15;
    float b = bias[c];
#pragma unroll
    for (int r = 0; r < 4; r++)
      zb[(w * 16 + quad * 4 + r) * 132 + c] = acc[nt][r] + b;
  }
  __syncthreads();
  int r = lane >> 2, seg = lane & 3;
  long grow = m0 + w * 16 + r;
  if (grow < M) {
    const float* zrow = &zb[(w * 16 + r) * 132 + seg * 32];
    u16* ip = inp + grow * 128 + seg * 32;
    u16* hp = hout + grow * 128 + seg * 32;
    u8*  qp = h8out + grow * 128 + seg * 32;
#pragma unroll
    for (int b = 0; b < 4; b++) {
      float zv[8];
      *(float4*)&zv[0] = *(const float4*)(zrow + b * 8);
      *(float4*)&zv[4] = *(const float4*)(zrow + b * 8 + 4);
      float rv[8];
#pragma unroll
      for (int jj = 0; jj < 8; jj++) rv[jj] = fmaxf(zv[jj], 0.f);
      *(ushort4*)(ip + b * 8)     = make_ushort4(f2b(zv[0]), f2b(zv[1]), f2b(zv[2]), f2b(zv[3]));
      *(ushort4*)(ip + b * 8 + 4) = make_ushort4(f2b(zv[4]), f2b(zv[5]), f2b(zv[6]), f2b(zv[7]));
      *(ushort4*)(hp + b * 8)     = make_ushort4(f2b(rv[0]), f2b(rv[1]), f2b(rv[2]), f2b(rv[3]));
      *(ushort4*)(hp + b * 8 + 4) = make_ushort4(f2b(rv[4]), f2b(rv[5]), f2b(rv[6]), f2b(rv[7]));
      unsigned q0 = 0, q1 = 0;
      q0 = __builtin_amdgcn_cvt_pk_fp8_f32(rv[0], rv[1], q0, false);
      q0 = __builtin_amdgcn_cvt_pk_fp8_f32(rv[2], rv[3], q0, true);
      q1 = __builtin_amdgcn_cvt_pk_fp8_f32(rv[4], rv[5], q1, false);
      q1 = __builtin_amdgcn_cvt_pk_fp8_f32(rv[6], rv[7], q1, true);
      *(uint2*)(qp + b * 8) = make_uint2(q0, q1);
    }
  }
}

// ------- fused SAGE layer: gather-mean(h8) -> LDS, MFMA(mean@Wl + h@Wr), epilogue -------
// h updated in place (blocks only read own rows of h bf16); h8out double-buffered (may be null)
__global__ __launch_bounds__(256) void sage_fused_k(
    const u8* __restrict__ h8, const int* __restrict__ rp,
    const int* __restrict__ col, const float* __restrict__ invdeg,
    u16* __restrict__ h, const u16* __restrict__ PL, const u16* __restrict__ PR,
    const float* __restrict__ bias, const u16* __restrict__ inp,
    u8* __restrict__ h8out, int M) {
  __shared__ float zb[8448];          // union: bf16 meanT[64][136] (17KB) / fp32 zb[64][132] (33KB)
  u16* meanT = (u16*)zb;
  int tid = threadIdx.x;
  int m0 = blockIdx.x * 64;
  // ---- phase A: gather fp8 means for the block's 64 rows into LDS ----
  {
    int hw = tid >> 5, lane = tid & 31;
    const u8* hp = h8 + lane * 4;
#pragma unroll 1
    for (int it = 0; it < 8; it++) {
      int node = m0 + it * 8 + hw;
      if (node < M) {
        int beg = rp[node], end = rp[node + 1];
        float a0 = 0.f, a1 = 0.f, a2 = 0.f, a3 = 0.f;
        int j = beg;
        for (; j + 3 < end; j += 4) {
          int s0 = col[j], s1 = col[j + 1], s2 = col[j + 2], s3 = col[j + 3];
          unsigned v0 = *(const unsigned*)(hp + ((long)s0 << 7));
          unsigned v1 = *(const unsigned*)(hp + ((long)s1 << 7));
          unsigned v2 = *(const unsigned*)(hp + ((long)s2 << 7));
          unsigned v3 = *(const unsigned*)(hp + ((long)s3 << 7));
          f32x2 p0 = __builtin_amdgcn_cvt_pk_f32_fp8(v0, false);
          f32x2 p1 = __builtin_amdgcn_cvt_pk_f32_fp8(v0, true);
          f32x2 p2 = __builtin_amdgcn_cvt_pk_f32_fp8(v1, false);
          f32x2 p3 = __builtin_amdgcn_cvt_pk_f32_fp8(v1, true);
          f32x2 p4 = __builtin_amdgcn_cvt_pk_f32_fp8(v2, false);
          f32x2 p5 = __builtin_amdgcn_cvt_pk_f32_fp8(v2, true);
          f32x2 p6 = __builtin_amdgcn_cvt_pk_f32_fp8(v3, false);
          f32x2 p7 = __builtin_amdgcn_cvt_pk_f32_fp8(v3, true);
          a0 += (p0[0] + p2[0]) + (p4[0] + p6[0]);
          a1 += (p0[1] + p2[1]) + (p4[1] + p6[1]);
          a2 += (p1[0] + p3[0]) + (p5[0] + p7[0]);
          a3 += (p1[1] + p3[1]) + (p5[1] + p7[1]);
        }
        for (; j < end; j++) {
          unsigned v0 = *(const unsigned*)(hp + ((long)col[j] << 7));
          f32x2 p0 = __builtin_amdgcn_cvt_pk_f32_fp8(v0, false);
          f32x2 p1 = __builtin_amdgcn_cvt_pk_f32_fp8(v0, true);
          a0 += p0[0]; a1 += p0[1]; a2 += p1[0]; a3 += p1[1];
        }
        float wd = invdeg[node];
        *(ushort4*)&meanT[(it * 8 + hw) * 136 + lane * 4] =
            make_ushort4(f2b(a0 * wd), f2b(a1 * wd), f2b(a2 * wd), f2b(a3 * wd));
      }
    }
  }
  __syncthreads();
  // ---- phase B: MFMA ----
  int w = tid >> 6, lane = tid & 63;
  int quad = lane >> 4, l15 = lane & 15;
  int rowa = m0 + w * 16 + l15; if (rowa > M - 1) rowa = M - 1;
  f32x4 acc[8] = {};
#pragma unroll
  for (int kt = 0; kt < 4; kt++) {
    bf16x8 am = *(const bf16x8*)&meanT[(w * 16 + l15) * 136 + kt * 32 + quad * 8];
    bf16x8 ar = *(const bf16x8*)(h + (long)rowa * 128 + kt * 32 + quad * 8);
    const u16* pl = PL + ((kt * 8) * 64 + lane) * 8;
    const u16* pr = PR + ((kt * 8) * 64 + lane) * 8;
#pragma unroll
    for (int nt = 0; nt < 8; nt++) {
      bf16x8 b0 = *(const bf16x8*)(pl + nt * 512);
      bf16x8 b1 = *(const bf16x8*)(pr + nt * 512);
      acc[nt] = __builtin_amdgcn_mfma_f32_16x16x32_bf16(am, b0, acc[nt], 0, 0, 0);
      acc[nt] = __builtin_amdgcn_mfma_f32_16x16x32_bf16(ar, b1, acc[nt], 0, 0, 0);
    }
  }
  __syncthreads();   // meanT reads done before zb overwrite
#pragma unroll
  for (int nt = 0; nt < 8; nt++) {
    int c = nt * 16 + l15;
    float b = bias[c];
#pragma unroll
    for (int r = 0; r < 4; r++)
      zb[(w * 16 + quad * 4 + r) * 132 + c] = fmaxf(acc[nt][r] + b, 0.f);
  }
  __syncthreads();
  int r = lane >> 2, seg = lane & 3;
  long grow = m0 + w * 16 + r;
  if (grow < M) {
    const float* zrow = &zb[(w * 16 + r) * 132 + seg * 32];
    const u16* ip = inp + grow * 128 + seg * 32;
    u16* op = h + grow * 128 + seg * 32;
#pragma unroll
    for (int b = 0; b < 4; b++) {
      float zv[8];
      *(float4*)&zv[0] = *(const float4*)(zrow + b * 8);
      *(float4*)&zv[4] = *(const float4*)(zrow + b * 8 + 4);
      uint2 iv0 = *(const uint2*)(ip + b * 8);
      uint2 iv1 = *(const uint2*)(ip + b * 8 + 4);
      float fv[8];
      fv[0] = zv[0] + 0.2f * bfl(iv0.x); fv[1] = zv[1] + 0.2f * bfh(iv0.x);
      fv[2] = zv[2] + 0.2f * bfl(iv0.y); fv[3] = zv[3] + 0.2f * bfh(iv0.y);
      fv[4] = zv[4] + 0.2f * bfl(iv1.x); fv[5] = zv[5] + 0.2f * bfh(iv1.x);
      fv[6] = zv[6] + 0.2f * bfl(iv1.y); fv[7] = zv[7] + 0.2f * bfh(iv1.y);
      *(ushort4*)(op + b * 8)     = make_ushort4(f2b(fv[0]), f2b(fv[1]), f2b(fv[2]), f2b(fv[3]));
      *(ushort4*)(op + b * 8 + 4) = make_ushort4(f2b(fv[4]), f2b(fv[5]), f2b(fv[6]), f2b(fv[7]));
      if (h8out) {
        unsigned q0 = 0, q1 = 0;
        q0 = __builtin_amdgcn_cvt_pk_fp8_f32(fv[0], fv[1], q0, false);
        q0 = __builtin_amdgcn_cvt_pk_fp8_f32(fv[2], fv[3], q0, true);
        q1 = __builtin_amdgcn_cvt_pk_fp8_f32(fv[4], fv[5], q1, false);
        q1 = __builtin_amdgcn_cvt_pk_fp8_f32(fv[6], fv[7], q1, true);
        *(uint2*)(h8out + grow * 128 + seg * 32 + b * 8) = make_uint2(q0, q1);
      }
    }
  }
}

// ------- output projection: gl = h@WloT, gr = h@WroT (bf16 [N,64] each, no bias) -------
__global__ __launch_bounds__(256) void out_proj_k(
    const u16* __restrict__ A, const u16* __restrict__ PLO,
    const u16* __restrict__ PRO, u16* __restrict__ gl, u16* __restrict__ gr, int M) {
  __shared__ float zb[64 * 132];
  int tid = threadIdx.x;
  int w = tid >> 6, lane = tid & 63;
  int quad = lane >> 4, l15 = lane & 15;
  int m0 = blockIdx.x * 64;
  int rowa = m0 + w * 16 + l15; if (rowa > M - 1) rowa = M - 1;
  f32x4 acc[8] = {};
#pragma unroll
  for (int kt = 0; kt < 4; kt++) {
    bf16x8 af = *(const bf16x8*)(A + (long)rowa * 128 + kt * 32 + quad * 8);
#pragma unroll
    for (int nt = 0; nt < 4; nt++) {
      bf16x8 b0 = *(const bf16x8*)(PLO + ((kt * 4 + nt) * 64 + lane) * 8);
      bf16x8 b1 = *(const bf16x8*)(PRO + ((kt * 4 + nt) * 64 + lane) * 8);
      acc[nt]     = __builtin_amdgcn_mfma_f32_16x16x32_bf16(af, b0, acc[nt], 0, 0, 0);
      acc[4 + nt] = __builtin_amdgcn_mfma_f32_16x16x32_bf16(af, b1, acc[4 + nt], 0, 0, 0);
    }
  }
  // zb cols 0-63 = gl, 64-127 = gr
#pragma unroll
  for (int nt = 0; nt < 4; nt++) {
    int c = nt * 16 + l15;
#pragma unroll
    for (int r = 0; r < 4; r++) {
      zb[(w * 16 + quad * 4 + r) * 132 + c]      = acc[nt][r];
      zb[(w * 16 + quad * 4 + r) * 132 + 64 + c] = acc[4 + nt][r];
    }
  }
  __syncthreads();
  int r = lane >> 2, seg = lane & 3;
  long grow = m0 + w * 16 + r;
  if (grow < M) {
    const float* zrow = &zb[(w * 16 + r) * 132 + seg * 32];
    u16* dp = (seg < 2) ? (gl + grow * 64 + seg * 32) : (gr + grow * 64 + (seg - 2) * 32);
#pragma unroll
    for (int b = 0; b < 4; b++) {
      float zv[8];
      *(float4*)&zv[0] = *(const float4*)(zrow + b * 8);
      *(float4*)&zv[4] = *(const float4*)(zrow + b * 8 + 4);
      *(ushort4*)(dp + b * 8)     = make_ushort4(f2b(zv[0]), f2b(zv[1]), f2b(zv[2]), f2b(zv[3]));
      *(ushort4*)(dp + b * 8 + 4) = make_ushort4(f2b(zv[4]), f2b(zv[5]), f2b(zv[6]), f2b(zv[7]));
    }
  }
}

// ------- output finalize: out = log_softmax(mean(gl) + gr + blo), half-wave per node -------
__global__ __launch_bounds__(256) void out_final_k(
    const u16* __restrict__ gl, const u16* __restrict__ gr,
    const float* __restrict__ blo, const int* __restrict__ rp,
    const int* __restrict__ col, const float* __restrict__ invdeg,
    float* __restrict__ outp) {
  int node = blockIdx.x * 8 + (threadIdx.x >> 5);
  int lane = threadIdx.x & 31;
  if (node >= N_NODES) return;
  int beg = rp[node], end = rp[node + 1];
  const u16* glp = gl + lane * 2;
  float a0 = 0.f, a1 = 0.f;
  int j = beg;
  for (; j + 3 < end; j += 4) {
    int s0 = col[j], s1 = col[j + 1], s2 = col[j + 2], s3 = col[j + 3];
    unsigned v0 = *(const unsigned*)(glp + ((long)s0 << 6));
    unsigned v1 = *(const unsigned*)(glp + ((long)s1 << 6));
    unsigned v2 = *(const unsigned*)(glp + ((long)s2 << 6));
    unsigned v3 = *(const unsigned*)(glp + ((long)s3 << 6));
    a0 += (bfl(v0) + bfl(v1)) + (bfl(v2) + bfl(v3));
    a1 += (bfh(v0) + bfh(v1)) + (bfh(v2) + bfh(v3));
  }
  for (; j < end; j++) {
    unsigned v0 = *(const unsigned*)(glp + ((long)col[j] << 6));
    a0 += bfl(v0); a1 += bfh(v0);
  }
  float wd = invdeg[node];
  unsigned g = *(const unsigned*)(gr + (long)node * 64 + lane * 2);
  float z0 = a0 * wd + bfl(g) + blo[lane * 2];
  float z1 = a1 * wd + bfh(g) + blo[lane * 2 + 1];
  float mx = fmaxf(z0, z1);
#pragma unroll
  for (int off = 16; off >= 1; off >>= 1) mx = fmaxf(mx, __shfl_xor(mx, off, 32));
  float s = __expf(z0 - mx) + __expf(z1 - mx);
#pragma unroll
  for (int off = 16; off >= 1; off >>= 1) s += __shfl_xor(s, off, 32);
  float ro = mx + __logf(s);
  float2 o = make_float2(z0 - ro, z1 - ro);
  *(float2*)(outp + (long)node * 64 + lane * 2) = o;
}

extern "C" void kernel_launch(void* const* d_in, const int* in_sizes, int n_in,
                              void* d_out, int out_size, void* d_ws, size_t ws_size,
                              hipStream_t stream) {
  if (ws_size < (size_t)WS_NEEDED) return;
  const float* x   = (const float*)d_in[0];
  const int*   ei  = (const int*)d_in[1];
  const float* Wp  = (const float*)d_in[2];
  const float* bp  = (const float*)d_in[3];
  const float* Wl  = (const float*)d_in[4];
  const float* bl  = (const float*)d_in[5];
  const float* Wr  = (const float*)d_in[6];
  const float* Wlo = (const float*)d_in[7];
  const float* blo = (const float*)d_in[8];
  const float* Wro = (const float*)d_in[9];
  float* out = (float*)d_out;
  char* ws = (char*)d_ws;
  int*   rp     = (int*)(ws + OFF_RP);
  float* invdeg = (float*)(ws + OFF_INVDEG);
  int*   bhist  = (int*)(ws + OFF_BHIST);
  int*   bbase  = (int*)(ws + OFF_BBASE);
  int*   gcur   = (int*)(ws + OFF_GCUR);
  uint2* pairs  = (uint2*)(ws + OFF_PAIRS);
  int*   col    = (int*)(ws + OFF_COL);
  u16*   pack   = (u16*)(ws + OFF_PACK);
  u16*   inp    = (u16*)(ws + OFF_INP);
  u16*   h      = (u16*)(ws + OFF_H);
  u8*    h8a    = (u8*)(ws + OFF_H8A);
  u8*    h8b    = (u8*)(ws + OFF_H8B);
  u16*   gl     = (u16*)(ws + OFF_GL);
  u16*   gr     = (u16*)(ws + OFF_GR);
  const int* srcv = ei;
  const int* dstv = ei + N_EDGES;

  hipMemsetAsync(ws + OFF_BHIST, 0, (NBUK + 1) * 4, stream);
  pack_weights_k<<<64, 256, 0, stream>>>(Wp, Wl, Wr, Wlo, Wro, pack);
  bhist_k<<<391, 256, 0, stream>>>(dstv, bhist);
  bscan_k<<<1, 512, 0, stream>>>(bhist, bbase, gcur, rp);
  part_k<<<NPBLK, 256, 0, stream>>>(srcv, dstv, gcur, pairs);
  csr_k<<<NBUK, 256, 0, stream>>>(pairs, bbase, rp, invdeg, col);

  int gblk = (N_NODES + 63) / 64;
  int fblk = (N_NODES + 7) / 8;

  inproj_mfma_k<<<gblk, 256, 0, stream>>>(x, pack + PK_WP, bp, inp, h, h8a, N_NODES);

  sage_fused_k<<<gblk, 256, 0, stream>>>(h8a, rp, col, invdeg, h,
                                         pack + PK_WL, pack + PK_WR, bl, inp, h8b, N_NODES);
  sage_fused_k<<<gblk, 256, 0, stream>>>(h8b, rp, col, invdeg, h,
                                         pack + PK_WL + 16384, pack + PK_WR + 16384,
                                         bl + 128, inp, h8a, N_NODES);
  sage_fused_k<<<gblk, 256, 0, stream>>>(h8a, rp, col, invdeg, h,
                                         pack + PK_WL + 32768, pack + PK_WR + 32768,
                                         bl + 256, inp, (u8*)nullptr, N_NODES);

  out_proj_k<<<gblk, 256, 0, stream>>>(h, pack + PK_WLO, pack + PK_WRO, gl, gr, N_NODES);
  out_final_k<<<fblk, 256, 0, stream>>>(gl, gr, blo, rp, col, invdeg, out);
}

// Round 6
// 545.404 us; speedup vs baseline: 2.6618x; 1.1285x over previous
//
#include <hip/hip_runtime.h>
#include <math.h>

#define N_NODES 100000
#define N_EDGES 1600000
#define NBUK 391          // ceil(N/256) buckets of 256 consecutive dst nodes
#define PCHUNK 8192       // edges per partition block
#define NPBLK 196         // ceil(E/PCHUNK)

typedef unsigned short u16;
typedef unsigned char u8;
typedef __bf16 bf16x8 __attribute__((ext_vector_type(8)));
typedef float f32x4 __attribute__((ext_vector_type(4)));
typedef float f32x2 __attribute__((ext_vector_type(2)));

// ---- workspace layout (bytes), 16B-aligned ----
#define OFF_RP      0u          // int[N+1]
#define OFF_INVDEG  400016u     // float[N]
#define OFF_BHIST   800016u     // int[392]
#define OFF_BBASE   801600u     // int[392]
#define OFF_GCUR    803200u     // int[392]
#define OFF_PAIRS   804800u     // uint2[E] = 12.8 MB
#define OFF_COL     13604800u   // int[E]
#define OFF_PACK    20004800u   // u16[131072] packed bf16 weight fragments
#define OFF_INP     20266944u   // u16[N*128] residual (pre-relu inProj), bf16
#define OFF_H       45866944u   // u16[N*128] h (in-place across layers), bf16
#define OFF_H8A     71466944u   // u8[N*128] fp8 copy of h (gather path), buffer A
#define OFF_H8B     84266944u   // u8[N*128] fp8 copy, buffer B
#define OFF_GL      97066944u   // u16[N*64] projected neighbor logits, bf16
#define OFF_GR      109866944u  // u16[N*64] projected root logits, bf16
#define OFF_MEAN    122666944u  // u16[N*128] aggregated mean, bf16
#define WS_NEEDED   148266944u

// packed-weight element offsets (u16 units)
#define PK_WP   0
#define PK_WL   16384
#define PK_WR   65536
#define PK_WLO  114688
#define PK_WRO  122880

__device__ __forceinline__ float bfl(unsigned u) {
  union { unsigned i; float f; } v; v.i = u << 16; return v.f;
}
__device__ __forceinline__ float bfh(unsigned u) {
  union { unsigned i; float f; } v; v.i = u & 0xFFFF0000u; return v.f;
}
__device__ __forceinline__ u16 f2b(float f) {       // RTNE
  union { float f; unsigned i; } v; v.f = f;
  unsigned r = (v.i + 0x7FFFu + ((v.i >> 16) & 1u)) >> 16;
  return (u16)r;
}

// ---------------- pack fp32 weights -> bf16 MFMA B-fragments ----------------
__global__ __launch_bounds__(256) void pack_weights_k(
    const float* __restrict__ Wp, const float* __restrict__ Wl,
    const float* __restrict__ Wr, const float* __restrict__ Wlo,
    const float* __restrict__ Wro, u16* __restrict__ P) {
  int t = blockIdx.x * 256 + threadIdx.x;
  if (t >= 16384) return;
  const float* W; u16* dst; int j; int NT;
  if (t < 2048)        { W = Wp;                    dst = P + PK_WP;                j = t;                 NT = 8; }
  else if (t < 8192)   { int m = (t - 2048) >> 11;  j = (t - 2048) & 2047;
                         W = Wl + (m << 14);        dst = P + PK_WL + (m << 14);    NT = 8; }
  else if (t < 14336)  { int m = (t - 8192) >> 11;  j = (t - 8192) & 2047;
                         W = Wr + (m << 14);        dst = P + PK_WR + (m << 14);    NT = 8; }
  else if (t < 15360)  { j = t - 14336;             W = Wlo;  dst = P + PK_WLO;     NT = 4; }
  else                 { j = t - 15360;             W = Wro;  dst = P + PK_WRO;     NT = 4; }
  int lane = j & 63;
  int nt, kt;
  if (NT == 8) { nt = (j >> 6) & 7; kt = j >> 9; }
  else         { nt = (j >> 6) & 3; kt = j >> 8; }
  int n  = nt * 16 + (lane & 15);
  int k0 = kt * 32 + ((lane >> 4) << 3);
  const float* s = W + n * 128 + k0;
  ushort4 lo = make_ushort4(f2b(s[0]), f2b(s[1]), f2b(s[2]), f2b(s[3]));
  ushort4 hi = make_ushort4(f2b(s[4]), f2b(s[5]), f2b(s[6]), f2b(s[7]));
  *(ushort4*)(dst + j * 8)     = lo;
  *(ushort4*)(dst + j * 8 + 4) = hi;
}

// ---------- bucket histogram ----------
__global__ __launch_bounds__(256) void bhist_k(const int* __restrict__ dst,
                                               int* __restrict__ bhist) {
  __shared__ int lc[NBUK];
  int t = threadIdx.x;
  for (int i = t; i < NBUK; i += 256) lc[i] = 0;
  __syncthreads();
  int base = blockIdx.x * 4096;
#pragma unroll
  for (int r = 0; r < 16; r++) {
    int i = base + r * 256 + t;
    if (i < N_EDGES) atomicAdd(&lc[dst[i] >> 8], 1);
  }
  __syncthreads();
  for (int i = t; i < NBUK; i += 256)
    if (lc[i]) atomicAdd(&bhist[i], lc[i]);
}

// ---------- single-block scan of bucket counts ----------
__global__ __launch_bounds__(512) void bscan_k(const int* __restrict__ bhist,
                                               int* __restrict__ bbase,
                                               int* __restrict__ gcur,
                                               int* __restrict__ rp) {
  __shared__ int s[512];
  int t = threadIdx.x;
  int v = (t < NBUK) ? bhist[t] : 0;
  s[t] = v;
  __syncthreads();
  for (int off = 1; off < 512; off <<= 1) {
    int u = (t >= off) ? s[t - off] : 0;
    __syncthreads();
    s[t] += u;
    __syncthreads();
  }
  if (t < NBUK) { int e = s[t] - v; bbase[t] = e; gcur[t] = e; }
  if (t == NBUK - 1) { bbase[NBUK] = s[t]; rp[N_NODES] = s[t]; }
}

// ---------- partition edges into bucket-contiguous (src,dst) pairs ----------
__global__ __launch_bounds__(256) void part_k(const int* __restrict__ src,
                                              const int* __restrict__ dst,
                                              int* __restrict__ gcur,
                                              uint2* __restrict__ pairs) {
  __shared__ int lcnt[NBUK + 1];
  __shared__ int lofs[512];
  __shared__ int cur[NBUK];
  __shared__ int gslot[NBUK];
  __shared__ uint2 stag[PCHUNK];
  int t = threadIdx.x;
  for (int i = t; i < NBUK + 1; i += 256) lcnt[i] = 0;
  __syncthreads();
  int base = blockIdx.x * PCHUNK;
#pragma unroll
  for (int r = 0; r < PCHUNK / 256; r++) {
    int i = base + r * 256 + t;
    if (i < N_EDGES) atomicAdd(&lcnt[dst[i] >> 8], 1);
  }
  __syncthreads();
  {
    int e1 = t + 256;
    lofs[t]  = (t  <= NBUK) ? lcnt[t]  : 0;
    lofs[e1] = (e1 <= NBUK) ? lcnt[e1] : 0;
    __syncthreads();
    for (int off = 1; off < 512; off <<= 1) {
      int a0 = (t  >= off) ? lofs[t  - off] : 0;
      int a1 = (e1 >= off) ? lofs[e1 - off] : 0;
      __syncthreads();
      lofs[t] += a0; lofs[e1] += a1;
      __syncthreads();
    }
    int o0 = lofs[t]  - ((t  <= NBUK) ? lcnt[t]  : 0);
    int o1 = lofs[e1] - ((e1 <= NBUK) ? lcnt[e1] : 0);
    __syncthreads();
    lofs[t] = o0; lofs[e1] = o1;
    __syncthreads();
  }
  for (int i = t; i < NBUK; i += 256) cur[i] = lofs[i];
  __syncthreads();
#pragma unroll
  for (int r = 0; r < PCHUNK / 256; r++) {
    int i = base + r * 256 + t;
    if (i < N_EDGES) {
      int d = dst[i];
      int slot = atomicAdd(&cur[d >> 8], 1);
      stag[slot] = make_uint2((unsigned)src[i], (unsigned)d);
    }
  }
  __syncthreads();
  for (int i = t; i < NBUK; i += 256)
    if (lcnt[i]) gslot[i] = atomicAdd(&gcur[i], lcnt[i]);
  __syncthreads();
  int total = lofs[NBUK];
  for (int p = t; p < total; p += 256) {
    uint2 pr = stag[p];
    int b = (int)(pr.y >> 8);
    pairs[gslot[b] + (p - lofs[b])] = pr;
  }
}

// ---------- per-bucket CSR finalize ----------
__global__ __launch_bounds__(256) void csr_k(const uint2* __restrict__ pairs,
                                             const int* __restrict__ bbase,
                                             int* __restrict__ rp,
                                             float* __restrict__ invdeg,
                                             int* __restrict__ col) {
  __shared__ int cnt[256];
  __shared__ int scn[256];
  __shared__ int cur[256];
  int b = blockIdx.x, t = threadIdx.x;
  int lo = bbase[b], hi = bbase[b + 1];
  cnt[t] = 0;
  __syncthreads();
  for (int p = lo + t; p < hi; p += 256)
    atomicAdd(&cnt[pairs[p].y & 255], 1);
  __syncthreads();
  int c = cnt[t];
  scn[t] = c;
  __syncthreads();
  for (int off = 1; off < 256; off <<= 1) {
    int v = (t >= off) ? scn[t - off] : 0;
    __syncthreads();
    scn[t] += v;
    __syncthreads();
  }
  int excl = scn[t] - c;
  int node = (b << 8) + t;
  if (node < N_NODES) {
    rp[node] = lo + excl;
    invdeg[node] = 1.0f / (float)(c > 1 ? c : 1);
  }
  cur[t] = lo + excl;
  __syncthreads();
  for (int p = lo + t; p < hi; p += 256) {
    uint2 pr = pairs[p];
    int slot = atomicAdd(&cur[pr.y & 255], 1);
    col[slot] = (int)pr.x;
  }
}

// ------- mean aggregation from fp8 rows: half-wave per node, 4B loads, x4 unroll -------
__global__ __launch_bounds__(256) void aggregate_fp8_k(const u8* __restrict__ h8,
                                                       const int* __restrict__ rp,
                                                       const int* __restrict__ col,
                                                       const float* __restrict__ invdeg,
                                                       u16* __restrict__ mean) {
  int node = blockIdx.x * 8 + (threadIdx.x >> 5);
  int lane = threadIdx.x & 31;
  if (node >= N_NODES) return;
  int beg = rp[node], end = rp[node + 1];
  const u8* hp = h8 + lane * 4;
  float a0 = 0.f, a1 = 0.f, a2 = 0.f, a3 = 0.f;
  int j = beg;
  for (; j + 3 < end; j += 4) {
    int s0 = col[j], s1 = col[j + 1], s2 = col[j + 2], s3 = col[j + 3];
    unsigned v0 = *(const unsigned*)(hp + ((long)s0 << 7));
    unsigned v1 = *(const unsigned*)(hp + ((long)s1 << 7));
    unsigned v2 = *(const unsigned*)(hp + ((long)s2 << 7));
    unsigned v3 = *(const unsigned*)(hp + ((long)s3 << 7));
    f32x2 p0 = __builtin_amdgcn_cvt_pk_f32_fp8(v0, false);
    f32x2 p1 = __builtin_amdgcn_cvt_pk_f32_fp8(v0, true);
    f32x2 p2 = __builtin_amdgcn_cvt_pk_f32_fp8(v1, false);
    f32x2 p3 = __builtin_amdgcn_cvt_pk_f32_fp8(v1, true);
    f32x2 p4 = __builtin_amdgcn_cvt_pk_f32_fp8(v2, false);
    f32x2 p5 = __builtin_amdgcn_cvt_pk_f32_fp8(v2, true);
    f32x2 p6 = __builtin_amdgcn_cvt_pk_f32_fp8(v3, false);
    f32x2 p7 = __builtin_amdgcn_cvt_pk_f32_fp8(v3, true);
    a0 += (p0[0] + p2[0]) + (p4[0] + p6[0]);
    a1 += (p0[1] + p2[1]) + (p4[1] + p6[1]);
    a2 += (p1[0] + p3[0]) + (p5[0] + p7[0]);
    a3 += (p1[1] + p3[1]) + (p5[1] + p7[1]);
  }
  for (; j < end; j++) {
    unsigned v0 = *(const unsigned*)(hp + ((long)col[j] << 7));
    f32x2 p0 = __builtin_amdgcn_cvt_pk_f32_fp8(v0, false);
    f32x2 p1 = __builtin_amdgcn_cvt_pk_f32_fp8(v0, true);
    a0 += p0[0]; a1 += p0[1]; a2 += p1[0]; a3 += p1[1];
  }
  float wd = invdeg[node];
  *(ushort4*)(mean + ((long)node << 7) + lane * 4) =
      make_ushort4(f2b(a0 * wd), f2b(a1 * wd), f2b(a2 * wd), f2b(a3 * wd));
}

// ------- inProj: z = x@WpT + bp; inp=bf16(z); h=bf16(relu(z)); h8=fp8(relu(z)) -------
__global__ __launch_bounds__(256) void inproj_mfma_k(
    const float* __restrict__ X, const u16* __restrict__ P,
    const float* __restrict__ bias,
    u16* __restrict__ inp, u16* __restrict__ hout, u8* __restrict__ h8out, int M) {
  __shared__ float zb[64 * 132];
  int tid = threadIdx.x;
  int w = tid >> 6, lane = tid & 63;
  int quad = lane >> 4, l15 = lane & 15;
  int m0 = blockIdx.x * 64;
  int rowa = m0 + w * 16 + l15; if (rowa > M - 1) rowa = M - 1;
  f32x4 acc[8] = {};
#pragma unroll
  for (int kt = 0; kt < 4; kt++) {
    const float* xr = X + (long)rowa * 128 + kt * 32 + quad * 8;
    float4 p0 = *(const float4*)xr;
    float4 p1 = *(const float4*)(xr + 4);
    union { ushort4 u4[2]; bf16x8 v; } fa;
    fa.u4[0] = make_ushort4(f2b(p0.x), f2b(p0.y), f2b(p0.z), f2b(p0.w));
    fa.u4[1] = make_ushort4(f2b(p1.x), f2b(p1.y), f2b(p1.z), f2b(p1.w));
    const u16* pb = P + ((kt * 8) * 64 + lane) * 8;
#pragma unroll
    for (int nt = 0; nt < 8; nt++) {
      bf16x8 bf = *(const bf16x8*)(pb + nt * 512);
      acc[nt] = __builtin_amdgcn_mfma_f32_16x16x32_bf16(fa.v, bf, acc[nt], 0, 0, 0);
    }
  }
#pragma unroll
  for (int nt = 0; nt < 8; nt++) {
    int c = nt * 16 + l15;
    float b = bias[c];
#pragma unroll
    for (int r = 0; r < 4; r++)
      zb[(w * 16 + quad * 4 + r) * 132 + c] = acc[nt][r] + b;
  }
  __syncthreads();
  int r = lane >> 2, seg = lane & 3;
  long grow = m0 + w * 16 + r;
  if (grow < M) {
    const float* zrow = &zb[(w * 16 + r) * 132 + seg * 32];
    u16* ip = inp + grow * 128 + seg * 32;
    u16* hp = hout + grow * 128 + seg * 32;
    u8*  qp = h8out + grow * 128 + seg * 32;
#pragma unroll
    for (int b = 0; b < 4; b++) {
      float zv[8];
      *(float4*)&zv[0] = *(const float4*)(zrow + b * 8);
      *(float4*)&zv[4] = *(const float4*)(zrow + b * 8 + 4);
      float rv[8];
#pragma unroll
      for (int jj = 0; jj < 8; jj++) rv[jj] = fmaxf(zv[jj], 0.f);
      *(ushort4*)(ip + b * 8)     = make_ushort4(f2b(zv[0]), f2b(zv[1]), f2b(zv[2]), f2b(zv[3]));
      *(ushort4*)(ip + b * 8 + 4) = make_ushort4(f2b(zv[4]), f2b(zv[5]), f2b(zv[6]), f2b(zv[7]));
      *(ushort4*)(hp + b * 8)     = make_ushort4(f2b(rv[0]), f2b(rv[1]), f2b(rv[2]), f2b(rv[3]));
      *(ushort4*)(hp + b * 8 + 4) = make_ushort4(f2b(rv[4]), f2b(rv[5]), f2b(rv[6]), f2b(rv[7]));
      unsigned q0 = 0, q1 = 0;
      q0 = __builtin_amdgcn_cvt_pk_fp8_f32(rv[0], rv[1], q0, false);
      q0 = __builtin_amdgcn_cvt_pk_fp8_f32(rv[2], rv[3], q0, true);
      q1 = __builtin_amdgcn_cvt_pk_fp8_f32(rv[4], rv[5], q1, false);
      q1 = __builtin_amdgcn_cvt_pk_fp8_f32(rv[6], rv[7], q1, true);
      *(uint2*)(qp + b * 8) = make_uint2(q0, q1);
    }
  }
}

// ------- SAGE layer (unfused): h = bf16(relu(mean@Wl + bl + h@Wr) + 0.2*inp), in-place;
//         also emits fp8 copy for next layer's gather (h8out may be null) -------
__global__ __launch_bounds__(256) void sage_mfma8_k(
    const u16* __restrict__ A0, const u16* __restrict__ P0,
    const u16* __restrict__ A1, const u16* __restrict__ P1,
    const float* __restrict__ bias, const u16* __restrict__ inp,
    u16* __restrict__ outp, u8* __restrict__ h8out, int M) {
  __shared__ float zb[64 * 132];
  int tid = threadIdx.x;
  int w = tid >> 6, lane = tid & 63;
  int quad = lane >> 4, l15 = lane & 15;
  int m0 = blockIdx.x * 64;
  int rowa = m0 + w * 16 + l15; if (rowa > M - 1) rowa = M - 1;
  f32x4 acc[8] = {};
#pragma unroll
  for (int kt = 0; kt < 4; kt++) {
    bf16x8 am = *(const bf16x8*)(A0 + (long)rowa * 128 + kt * 32 + quad * 8);
    bf16x8 ar = *(const bf16x8*)(A1 + (long)rowa * 128 + kt * 32 + quad * 8);
    const u16* pl = P0 + ((kt * 8) * 64 + lane) * 8;
    const u16* pr = P1 + ((kt * 8) * 64 + lane) * 8;
#pragma unroll
    for (int nt = 0; nt < 8; nt++) {
      bf16x8 b0 = *(const bf16x8*)(pl + nt * 512);
      bf16x8 b1 = *(const bf16x8*)(pr + nt * 512);
      acc[nt] = __builtin_amdgcn_mfma_f32_16x16x32_bf16(am, b0, acc[nt], 0, 0, 0);
      acc[nt] = __builtin_amdgcn_mfma_f32_16x16x32_bf16(ar, b1, acc[nt], 0, 0, 0);
    }
  }
#pragma unroll
  for (int nt = 0; nt < 8; nt++) {
    int c = nt * 16 + l15;
    float b = bias[c];
#pragma unroll
    for (int r = 0; r < 4; r++)
      zb[(w * 16 + quad * 4 + r) * 132 + c] = fmaxf(acc[nt][r] + b, 0.f);
  }
  __syncthreads();
  int r = lane >> 2, seg = lane & 3;
  long grow = m0 + w * 16 + r;
  if (grow < M) {
    const float* zrow = &zb[(w * 16 + r) * 132 + seg * 32];
    const u16* ip = inp + grow * 128 + seg * 32;
    u16* op = outp + grow * 128 + seg * 32;
#pragma unroll
    for (int b = 0; b < 4; b++) {
      float zv[8];
      *(float4*)&zv[0] = *(const float4*)(zrow + b * 8);
      *(float4*)&zv[4] = *(const float4*)(zrow + b * 8 + 4);
      uint2 iv0 = *(const uint2*)(ip + b * 8);
      uint2 iv1 = *(const uint2*)(ip + b * 8 + 4);
      float fv[8];
      fv[0] = zv[0] + 0.2f * bfl(iv0.x); fv[1] = zv[1] + 0.2f * bfh(iv0.x);
      fv[2] = zv[2] + 0.2f * bfl(iv0.y); fv[3] = zv[3] + 0.2f * bfh(iv0.y);
      fv[4] = zv[4] + 0.2f * bfl(iv1.x); fv[5] = zv[5] + 0.2f * bfh(iv1.x);
      fv[6] = zv[6] + 0.2f * bfl(iv1.y); fv[7] = zv[7] + 0.2f * bfh(iv1.y);
      *(ushort4*)(op + b * 8)     = make_ushort4(f2b(fv[0]), f2b(fv[1]), f2b(fv[2]), f2b(fv[3]));
      *(ushort4*)(op + b * 8 + 4) = make_ushort4(f2b(fv[4]), f2b(fv[5]), f2b(fv[6]), f2b(fv[7]));
      if (h8out) {
        unsigned q0 = 0, q1 = 0;
        q0 = __builtin_amdgcn_cvt_pk_fp8_f32(fv[0], fv[1], q0, false);
        q0 = __builtin_amdgcn_cvt_pk_fp8_f32(fv[2], fv[3], q0, true);
        q1 = __builtin_amdgcn_cvt_pk_fp8_f32(fv[4], fv[5], q1, false);
        q1 = __builtin_amdgcn_cvt_pk_fp8_f32(fv[6], fv[7], q1, true);
        *(uint2*)(h8out + grow * 128 + seg * 32 + b * 8) = make_uint2(q0, q1);
      }
    }
  }
}

// ------- output projection: gl = h@WloT, gr = h@WroT (bf16 [N,64] each, no bias) -------
__global__ __launch_bounds__(256) void out_proj_k(
    const u16* __restrict__ A, const u16* __restrict__ PLO,
    const u16* __restrict__ PRO, u16* __restrict__ gl, u16* __restrict__ gr, int M) {
  __shared__ float zb[64 * 132];
  int tid = threadIdx.x;
  int w = tid >> 6, lane = tid & 63;
  int quad = lane >> 4, l15 = lane & 15;
  int m0 = blockIdx.x * 64;
  int rowa = m0 + w * 16 + l15; if (rowa > M - 1) rowa = M - 1;
  f32x4 acc[8] = {};
#pragma unroll
  for (int kt = 0; kt < 4; kt++) {
    bf16x8 af = *(const bf16x8*)(A + (long)rowa * 128 + kt * 32 + quad * 8);
#pragma unroll
    for (int nt = 0; nt < 4; nt++) {
      bf16x8 b0 = *(const bf16x8*)(PLO + ((kt * 4 + nt) * 64 + lane) * 8);
      bf16x8 b1 = *(const bf16x8*)(PRO + ((kt * 4 + nt) * 64 + lane) * 8);
      acc[nt]     = __builtin_amdgcn_mfma_f32_16x16x32_bf16(af, b0, acc[nt], 0, 0, 0);
      acc[4 + nt] = __builtin_amdgcn_mfma_f32_16x16x32_bf16(af, b1, acc[4 + nt], 0, 0, 0);
    }
  }
  // zb cols 0-63 = gl, 64-127 = gr
#pragma unroll
  for (int nt = 0; nt < 4; nt++) {
    int c = nt * 16 + l15;
#pragma unroll
    for (int r = 0; r < 4; r++) {
      zb[(w * 16 + quad * 4 + r) * 132 + c]      = acc[nt][r];
      zb[(w * 16 + quad * 4 + r) * 132 + 64 + c] = acc[4 + nt][r];
    }
  }
  __syncthreads();
  int r = lane >> 2, seg = lane & 3;
  long grow = m0 + w * 16 + r;
  if (grow < M) {
    const float* zrow = &zb[(w * 16 + r) * 132 + seg * 32];
    u16* dp = (seg < 2) ? (gl + grow * 64 + seg * 32) : (gr + grow * 64 + (seg - 2) * 32);
#pragma unroll
    for (int b = 0; b < 4; b++) {
      float zv[8];
      *(float4*)&zv[0] = *(const float4*)(zrow + b * 8);
      *(float4*)&zv[4] = *(const float4*)(zrow + b * 8 + 4);
      *(ushort4*)(dp + b * 8)     = make_ushort4(f2b(zv[0]), f2b(zv[1]), f2b(zv[2]), f2b(zv[3]));
      *(ushort4*)(dp + b * 8 + 4) = make_ushort4(f2b(zv[4]), f2b(zv[5]), f2b(zv[6]), f2b(zv[7]));
    }
  }
}

// ------- output finalize: out = log_softmax(mean(gl) + gr + blo), half-wave per node -------
__global__ __launch_bounds__(256) void out_final_k(
    const u16* __restrict__ gl, const u16* __restrict__ gr,
    const float* __restrict__ blo, const int* __restrict__ rp,
    const int* __restrict__ col, const float* __restrict__ invdeg,
    float* __restrict__ outp) {
  int node = blockIdx.x * 8 + (threadIdx.x >> 5);
  int lane = threadIdx.x & 31;
  if (node >= N_NODES) return;
  int beg = rp[node], end = rp[node + 1];
  const u16* glp = gl + lane * 2;
  float a0 = 0.f, a1 = 0.f;
  int j = beg;
  for (; j + 3 < end; j += 4) {
    int s0 = col[j], s1 = col[j + 1], s2 = col[j + 2], s3 = col[j + 3];
    unsigned v0 = *(const unsigned*)(glp + ((long)s0 << 6));
    unsigned v1 = *(const unsigned*)(glp + ((long)s1 << 6));
    unsigned v2 = *(const unsigned*)(glp + ((long)s2 << 6));
    unsigned v3 = *(const unsigned*)(glp + ((long)s3 << 6));
    a0 += (bfl(v0) + bfl(v1)) + (bfl(v2) + bfl(v3));
    a1 += (bfh(v0) + bfh(v1)) + (bfh(v2) + bfh(v3));
  }
  for (; j < end; j++) {
    unsigned v0 = *(const unsigned*)(glp + ((long)col[j] << 6));
    a0 += bfl(v0); a1 += bfh(v0);
  }
  float wd = invdeg[node];
  unsigned g = *(const unsigned*)(gr + (long)node * 64 + lane * 2);
  float z0 = a0 * wd + bfl(g) + blo[lane * 2];
  float z1 = a1 * wd + bfh(g) + blo[lane * 2 + 1];
  float mx = fmaxf(z0, z1);
#pragma unroll
  for (int off = 16; off >= 1; off >>= 1) mx = fmaxf(mx, __shfl_xor(mx, off, 32));
  float s = __expf(z0 - mx) + __expf(z1 - mx);
#pragma unroll
  for (int off = 16; off >= 1; off >>= 1) s += __shfl_xor(s, off, 32);
  float ro = mx + __logf(s);
  float2 o = make_float2(z0 - ro, z1 - ro);
  *(float2*)(outp + (long)node * 64 + lane * 2) = o;
}

extern "C" void kernel_launch(void* const* d_in, const int* in_sizes, int n_in,
                              void* d_out, int out_size, void* d_ws, size_t ws_size,
                              hipStream_t stream) {
  if (ws_size < (size_t)WS_NEEDED) return;
  const float* x   = (const float*)d_in[0];
  const int*   ei  = (const int*)d_in[1];
  const float* Wp  = (const float*)d_in[2];
  const float* bp  = (const float*)d_in[3];
  const float* Wl  = (const float*)d_in[4];
  const float* bl  = (const float*)d_in[5];
  const float* Wr  = (const float*)d_in[6];
  const float* Wlo = (const float*)d_in[7];
  const float* blo = (const float*)d_in[8];
  const float* Wro = (const float*)d_in[9];
  float* out = (float*)d_out;
  char* ws = (char*)d_ws;
  int*   rp     = (int*)(ws + OFF_RP);
  float* invdeg = (float*)(ws + OFF_INVDEG);
  int*   bhist  = (int*)(ws + OFF_BHIST);
  int*   bbase  = (int*)(ws + OFF_BBASE);
  int*   gcur   = (int*)(ws + OFF_GCUR);
  uint2* pairs  = (uint2*)(ws + OFF_PAIRS);
  int*   col    = (int*)(ws + OFF_COL);
  u16*   pack   = (u16*)(ws + OFF_PACK);
  u16*   inp    = (u16*)(ws + OFF_INP);
  u16*   h      = (u16*)(ws + OFF_H);
  u8*    h8a    = (u8*)(ws + OFF_H8A);
  u8*    h8b    = (u8*)(ws + OFF_H8B);
  u16*   gl     = (u16*)(ws + OFF_GL);
  u16*   gr     = (u16*)(ws + OFF_GR);
  u16*   mean   = (u16*)(ws + OFF_MEAN);
  const int* srcv = ei;
  const int* dstv = ei + N_EDGES;

  hipMemsetAsync(ws + OFF_BHIST, 0, (NBUK + 1) * 4, stream);
  pack_weights_k<<<64, 256, 0, stream>>>(Wp, Wl, Wr, Wlo, Wro, pack);
  bhist_k<<<391, 256, 0, stream>>>(dstv, bhist);
  bscan_k<<<1, 512, 0, stream>>>(bhist, bbase, gcur, rp);
  part_k<<<NPBLK, 256, 0, stream>>>(srcv, dstv, gcur, pairs);
  csr_k<<<NBUK, 256, 0, stream>>>(pairs, bbase, rp, invdeg, col);

  int gblk = (N_NODES + 63) / 64;
  int fblk = (N_NODES + 7) / 8;

  inproj_mfma_k<<<gblk, 256, 0, stream>>>(x, pack + PK_WP, bp, inp, h, h8a, N_NODES);

  aggregate_fp8_k<<<fblk, 256, 0, stream>>>(h8a, rp, col, invdeg, mean);
  sage_mfma8_k<<<gblk, 256, 0, stream>>>(mean, pack + PK_WL, h, pack + PK_WR,
                                         bl, inp, h, h8b, N_NODES);
  aggregate_fp8_k<<<fblk, 256, 0, stream>>>(h8b, rp, col, invdeg, mean);
  sage_mfma8_k<<<gblk, 256, 0, stream>>>(mean, pack + PK_WL + 16384, h, pack + PK_WR + 16384,
                                         bl + 128, inp, h, h8a, N_NODES);
  aggregate_fp8_k<<<fblk, 256, 0, stream>>>(h8a, rp, col, invdeg, mean);
  sage_mfma8_k<<<gblk, 256, 0, stream>>>(mean, pack + PK_WL + 32768, h, pack + PK_WR + 32768,
                                         bl + 256, inp, h, (u8*)nullptr, N_NODES);

  out_proj_k<<<gblk, 256, 0, stream>>>(h, pack + PK_WLO, pack + PK_WRO, gl, gr, N_NODES);
  out_final_k<<<fblk, 256, 0, stream>>>(gl, gr, blo, rp, col, invdeg, out);
}